// Round 2
// baseline (7207.721 us; speedup 1.0000x reference)
//
#include <hip/hip_runtime.h>
#include <hip/hip_bf16.h>

typedef __hip_bfloat16 bf16;

#define DEV __device__ __forceinline__

DEV float bf2f(bf16 v) { return __bfloat162float(v); }
DEV bf16 f2bf(float v) { return __float2bfloat16(v); }
DEV float gelu_exact(float x) { return 0.5f * x * (1.0f + erff(x * 0.70710678118654752f)); }

// load a "reference float32" parameter that may physically be bf16 or fp32
DEV float ldw(const void* p, long i, int isb) {
  return isb ? __bfloat162float(((const bf16*)p)[i]) : ((const float*)p)[i];
}

// ---------------- dtype detection ----------------
// bf16 N(0,1) data: every halfword exponent <= ~129. fp32 data read as halfwords:
// ~45% of low-mantissa words have exponent >= 138. flag=1 -> buffers are bf16.
__global__ void k_detect(const unsigned short* __restrict__ u, int* __restrict__ flag) {
  __shared__ int bad;
  if (threadIdx.x == 0) bad = 0;
  __syncthreads();
  for (int i = threadIdx.x; i < 8192; i += 256) {
    int expo = (u[i] >> 7) & 0xFF;
    if (expo >= 138) atomicOr(&bad, 1);
  }
  __syncthreads();
  if (threadIdx.x == 0) *flag = bad ? 0 : 1;
}

// ---------------- convert (bf16|fp32) -> fp32 ----------------
__global__ void k_cvt(const void* __restrict__ s, float* __restrict__ d, int n,
                      const int* __restrict__ fl) {
  int isb = *fl;
  int i = blockIdx.x * blockDim.x + threadIdx.x;
  if (i < n) d[i] = ldw(s, i, isb);
}

// ---------------- local correlation (level 1) ----------------
// corrT[(b*1024+p)*49 + c] layout: rows=token, cols=disp (ready as GEMM A)
__global__ void k_corr(const float* __restrict__ F2, float* __restrict__ corrT) {
  __shared__ float f1v[128];
  int p = blockIdx.x;          // pixel 0..1023
  int b = blockIdx.y;          // pair 0..1
  int t = threadIdx.x;         // 64 threads
  const float* f1 = F2 + (long)b * 131072;
  const float* f2 = F2 + (long)(b + 1) * 131072;
  f1v[t]      = f1[t * 1024 + p];
  f1v[t + 64] = f1[(t + 64) * 1024 + p];
  __syncthreads();
  if (t < 49) {
    int dy = t / 7 - 3, dx = t % 7 - 3;
    int h = p >> 5, w = p & 31;
    int p2 = (((h - dy) & 31) << 5) | ((w - dx) & 31);
    float s = 0.0f;
    for (int c = 0; c < 128; ++c) s += f1v[c] * f2[c * 1024 + p2];
    corrT[((long)b * 1024 + p) * 49 + t] = s * 0.08838834764831845f; // 1/sqrt(128)
  }
}

// ---------------- LayerNorm (D=192), one wave per row ----------------
__global__ void k_ln(const float* __restrict__ src, float* __restrict__ dst,
                     const void* __restrict__ w, const void* __restrict__ b,
                     const int* __restrict__ fl) {
  int isb = *fl;
  int row = blockIdx.x;
  int t = threadIdx.x; // 64
  const float* s = src + (long)row * 192;
  float e0 = s[t], e1 = s[t + 64], e2 = s[t + 128];
  float sum = e0 + e1 + e2;
  for (int o = 32; o; o >>= 1) sum += __shfl_xor(sum, o);
  float mean = sum * (1.0f / 192.0f);
  float d0 = e0 - mean, d1 = e1 - mean, d2 = e2 - mean;
  float vs = d0 * d0 + d1 * d1 + d2 * d2;
  for (int o = 32; o; o >>= 1) vs += __shfl_xor(vs, o);
  float rstd = rsqrtf(vs * (1.0f / 192.0f) + 1e-5f);
  float* o_ = dst + (long)row * 192;
  o_[t]       = d0 * rstd * ldw(w, t, isb)       + ldw(b, t, isb);
  o_[t + 64]  = d1 * rstd * ldw(w, t + 64, isb)  + ldw(b, t + 64, isb);
  o_[t + 128] = d2 * rstd * ldw(w, t + 128, isb) + ldw(b, t + 128, isb);
}

// ---------------- GEMM: C(MxN) = A(MxK) @ W(NxK)^T + bias (+res) (+gelu) ----------------
// BM=BN=64, BK=16, 256 threads, 4x4 microtile.
template <int ACT, bool HASRES>
__global__ __launch_bounds__(256) void k_gemm(const float* __restrict__ A, const void* __restrict__ W,
                                              const void* __restrict__ bias, const float* __restrict__ res,
                                              float* __restrict__ C, int M, int N, int K,
                                              const int* __restrict__ fl) {
  int isb = *fl;
  __shared__ float As[16][65];
  __shared__ float Ws[16][65];
  int tid = threadIdx.x;
  int tx = tid & 15, ty = tid >> 4;
  int m0 = blockIdx.y * 64, n0 = blockIdx.x * 64;
  float acc[4][4] = {};
  int nk = (K + 15) >> 4;
  for (int kt = 0; kt < nk; ++kt) {
    int k0 = kt << 4;
#pragma unroll
    for (int i = 0; i < 4; ++i) {
      int idx = tid + i * 256;
      int mm = idx >> 4, kk = idx & 15;
      int gm = m0 + mm, gk = k0 + kk;
      As[kk][mm] = (gm < M && gk < K) ? A[(long)gm * K + gk] : 0.0f;
      int gn = n0 + mm;
      Ws[kk][mm] = (gn < N && gk < K) ? ldw(W, (long)gn * K + gk, isb) : 0.0f;
    }
    __syncthreads();
#pragma unroll
    for (int kk = 0; kk < 16; ++kk) {
      float a[4], w[4];
#pragma unroll
      for (int i = 0; i < 4; ++i) a[i] = As[kk][ty * 4 + i];
#pragma unroll
      for (int j = 0; j < 4; ++j) w[j] = Ws[kk][tx * 4 + j];
#pragma unroll
      for (int i = 0; i < 4; ++i)
#pragma unroll
        for (int j = 0; j < 4; ++j) acc[i][j] += a[i] * w[j];
    }
    __syncthreads();
  }
#pragma unroll
  for (int i = 0; i < 4; ++i) {
    int gm = m0 + ty * 4 + i;
    if (gm >= M) continue;
#pragma unroll
    for (int j = 0; j < 4; ++j) {
      int gn = n0 + tx * 4 + j;
      if (gn >= N) continue;
      float v = acc[i][j] + ldw(bias, gn, isb);
      if (HASRES) v += res[(long)gm * N + gn];
      if (ACT == 1) v = gelu_exact(v);
      C[(long)gm * N + gn] = v;
    }
  }
}

// ---------------- fused attention (flash, Br=16, Bc=64), heads=4, HD=48, N=1024/pair --------
__global__ __launch_bounds__(256) void k_attn(const float* __restrict__ qkv, float* __restrict__ y) {
  __shared__ float Qs[16][49], Ks[64][49], Vs[64][49], S[16][64], O[16][49];
  __shared__ float mS[16], lS[16], aS[16];
  int tid = threadIdx.x;
  int h = blockIdx.y, b = blockIdx.z;
  int q0 = blockIdx.x * 16;
  const float* Q = qkv + (long)b * 1024 * 576;
  for (int i = tid; i < 768; i += 256) {
    int r = i / 48, d = i % 48;
    Qs[r][d] = Q[(q0 + r) * 576 + h * 48 + d] * 0.14433756729740643f; // 1/sqrt(48)
    O[r][d] = 0.0f;
  }
  if (tid < 16) { mS[tid] = -1e30f; lS[tid] = 0.0f; }
  __syncthreads();
  for (int kc = 0; kc < 16; ++kc) {
    int k0 = kc * 64;
    for (int i = tid; i < 3072; i += 256) {
      int r = i / 48, d = i % 48;
      Ks[r][d] = Q[(k0 + r) * 576 + 192 + h * 48 + d];
      Vs[r][d] = Q[(k0 + r) * 576 + 384 + h * 48 + d];
    }
    __syncthreads();
#pragma unroll
    for (int i = 0; i < 4; ++i) {
      int e = tid + i * 256;
      int r = e >> 6, c = e & 63;
      float s = 0.0f;
#pragma unroll
      for (int d = 0; d < 48; ++d) s += Qs[r][d] * Ks[c][d];
      S[r][c] = s;
    }
    __syncthreads();
    if (tid < 16) {
      int r = tid;
      float m = mS[r], mx = m;
      for (int c = 0; c < 64; ++c) mx = fmaxf(mx, S[r][c]);
      float alpha = __expf(m - mx);
      float sum = 0.0f;
      for (int c = 0; c < 64; ++c) { float p = __expf(S[r][c] - mx); S[r][c] = p; sum += p; }
      lS[r] = lS[r] * alpha + sum;
      mS[r] = mx; aS[r] = alpha;
    }
    __syncthreads();
    for (int i = tid; i < 768; i += 256) {
      int r = i / 48, d = i % 48;
      float o = O[r][d] * aS[r];
#pragma unroll
      for (int c = 0; c < 64; ++c) o += S[r][c] * Vs[c][d];
      O[r][d] = o;
    }
    __syncthreads();
  }
  float* Y = y + (long)b * 1024 * 192;
  for (int i = tid; i < 768; i += 256) {
    int r = i / 48, d = i % 48;
    Y[(q0 + r) * 192 + h * 48 + d] = O[r][d] / lS[r];
  }
}

// ---------------- EMA: x[pair1] = 0.8*x[pair1] + 0.2*x[pair0] ----------------
__global__ void k_ema(float* __restrict__ x) {
  int i = blockIdx.x * blockDim.x + threadIdx.x;
  if (i < 196608) x[196608 + i] = 0.8f * x[196608 + i] + 0.2f * x[i];
}

// ---------------- fv (2048x2) -> flow [b][2][1024] ----------------
__global__ void k_fv2flow(const float* __restrict__ fv, float* __restrict__ cur) {
  int i = blockIdx.x * blockDim.x + threadIdx.x;
  if (i < 4096) {
    int b = i >> 11, r = i & 2047;
    int c = r >> 10, p = r & 1023;
    cur[i] = fv[(long)(b * 1024 + p) * 2 + c];
  }
}

// ---------------- warp (bilinear, border clamp); img for pair b is imgbase[(b+1)] --------
__global__ void k_warp(const float* __restrict__ imgbase, const float* __restrict__ flow,
                       float* __restrict__ out, int C, int H, int W) {
  int HW = H * W;
  int per = C * HW;
  int i = blockIdx.x * blockDim.x + threadIdx.x;
  if (i >= 2 * per) return;
  int b = i / per;
  int rem = i - b * per;
  int c = rem / HW;
  int p = rem - c * HW;
  int h = p / W, w = p - h * W;
  const float* img = imgbase + (long)(b + 1) * per;
  const float* fl = flow + (long)b * 2 * HW;
  float x = fminf(fmaxf((float)w + fl[p], 0.0f), (float)(W - 1));
  float yy = fminf(fmaxf((float)h + fl[HW + p], 0.0f), (float)(H - 1));
  int x0 = (int)floorf(x), y0 = (int)floorf(yy);
  int x1 = min(x0 + 1, W - 1), y1 = min(y0 + 1, H - 1);
  float wx = x - (float)x0, wy = yy - (float)y0;
  const float* ic = img + (long)c * HW;
  float v00 = ic[y0 * W + x0], v01 = ic[y0 * W + x1];
  float v10 = ic[y1 * W + x0], v11 = ic[y1 * W + x1];
  out[i] = v00 * (1 - wx) * (1 - wy) + v01 * wx * (1 - wy) + v10 * (1 - wx) * wy + v11 * wx * wy;
}

// ---------------- direct 3x3 conv, pad=1, implicit 3-segment concat input, batched over 2 pairs
__global__ void k_conv3x3(const float* __restrict__ s0, int c0, long s0bs,
                          const float* __restrict__ s1, int c1, long s1bs,
                          const float* __restrict__ s2, int c2, long s2bs,
                          const void* __restrict__ wgt, const void* __restrict__ bias,
                          float* __restrict__ out, long outbs,
                          const float* __restrict__ res, long resbs,
                          int H, int W, int OC, int act, const int* __restrict__ flg) {
  int isb = *flg;
  int HW = H * W;
  int per = OC * HW;
  int i = blockIdx.x * blockDim.x + threadIdx.x;
  if (i >= 2 * per) return;
  int b = i / per;
  int rem = i - b * per;
  int oc = rem / HW;
  int p = rem - oc * HW;
  int h = p / W, w = p - h * W;
  int ICT = c0 + c1 + c2;
  float acc = ldw(bias, oc, isb);
  const float* segs[3] = { s0 ? s0 + (long)b * s0bs : nullptr,
                           s1 ? s1 + (long)b * s1bs : nullptr,
                           s2 ? s2 + (long)b * s2bs : nullptr };
  int cnts[3] = { c0, c1, c2 };
  int icb = 0;
  for (int sg = 0; sg < 3; ++sg) {
    const float* sp = segs[sg];
    int cc = cnts[sg];
    if (!sp || cc == 0) continue;
    for (int ic = 0; ic < cc; ++ic) {
      const float* ip = sp + (long)ic * HW;
      long wbase = ((long)oc * ICT + icb + ic) * 9;
#pragma unroll
      for (int ky = 0; ky < 3; ++ky) {
        int yy = h + ky - 1;
        if (yy < 0 || yy >= H) continue;
        const float* rowp = ip + yy * W;
#pragma unroll
        for (int kx = 0; kx < 3; ++kx) {
          int xx = w + kx - 1;
          if (xx < 0 || xx >= W) continue;
          acc += rowp[xx] * ldw(wgt, wbase + ky * 3 + kx, isb);
        }
      }
    }
    icb += cc;
  }
  if (act) acc = gelu_exact(acc);
  float v = acc;
  if (res) v += res[(long)b * resbs + rem];
  out[(long)b * outbs + rem] = v;
}

// ---------------- 2x align-corners bilinear upsample (2x2x32x32 -> 2x2x64x64) -------------
__global__ void k_upsample(const float* __restrict__ in, float* __restrict__ out) {
  int i = blockIdx.x * blockDim.x + threadIdx.x;
  if (i >= 2 * 2 * 64 * 64) return;
  int p = i & 4095;
  int bc = i >> 12;
  int oy = p >> 6, ox = p & 63;
  float sx = ox * (31.0f / 63.0f), sy = oy * (31.0f / 63.0f);
  int x0 = (int)sx, y0 = (int)sy;
  int x1 = min(x0 + 1, 31), y1 = min(y0 + 1, 31);
  float wx = sx - x0, wy = sy - y0;
  const float* ic = in + (long)bc * 1024;
  out[i] = ic[y0 * 32 + x0] * (1 - wx) * (1 - wy) + ic[y0 * 32 + x1] * wx * (1 - wy)
         + ic[y1 * 32 + x0] * (1 - wx) * wy      + ic[y1 * 32 + x1] * wx * wy;
}

// ---------------- final write (fp32 -> bf16|fp32 per detected dtype) ----------------
__global__ void k_out(const float* __restrict__ cur2, void* __restrict__ out,
                      const int* __restrict__ fl) {
  int isb = *fl;
  int i = blockIdx.x * blockDim.x + threadIdx.x;
  if (i < 16384) {
    if (isb) ((bf16*)out)[i] = f2bf(cur2[i]);
    else ((float*)out)[i] = cur2[i];
  }
}

extern "C" void kernel_launch(void* const* d_in, const int* in_sizes, int n_in,
                              void* d_out, int out_size, void* d_ws, size_t ws_size,
                              hipStream_t stream) {
  const void* feats_l1 = d_in[0];
  const void* feats_l2 = d_in[1];
  // d_in[2] = feats_l3 : dead (never reaches the output)
  const char* tok_w_c = (const char*)d_in[3];
  const char* tok_b_c = (const char*)d_in[4];
  const void* lcm_ln1_w = d_in[5];
  const void* lcm_ln1_b = d_in[6];
  const void* lcm_in_w  = d_in[7];
  const void* lcm_in_b  = d_in[8];
  const void* lcm_out_w = d_in[9];
  const void* lcm_out_b = d_in[10];
  const void* lcm_ln2_w = d_in[11];
  const void* lcm_ln2_b = d_in[12];
  const void* lcm_mlp_w1 = d_in[13];
  const void* lcm_mlp_b1 = d_in[14];
  const void* lcm_mlp_w2 = d_in[15];
  const void* lcm_mlp_b2 = d_in[16];
  const void* gtr_ln1_w = d_in[17];
  const void* gtr_ln1_b = d_in[18];
  const void* gtr_in_w  = d_in[19];
  const void* gtr_in_b  = d_in[20];
  const void* gtr_out_w = d_in[21];
  const void* gtr_out_b = d_in[22];
  const void* gtr_ln2_w = d_in[23];
  const void* gtr_ln2_b = d_in[24];
  const void* gtr_mlp_w1 = d_in[25];
  const void* gtr_mlp_b1 = d_in[26];
  const void* gtr_mlp_w2 = d_in[27];
  const void* gtr_mlp_b2 = d_in[28];
  const void* head_w1 = d_in[29];
  const void* head_b1 = d_in[30];
  const void* head_w2 = d_in[31];
  const void* head_b2 = d_in[32];
  const void* ref1_w1 = d_in[33];
  const void* ref1_b1 = d_in[34];
  const void* ref1_w2 = d_in[35];
  const void* ref1_b2 = d_in[36];
  const void* ref0_w1 = d_in[37];
  const void* ref0_b1 = d_in[38];
  const void* ref0_w2 = d_in[39];
  const void* ref0_b2 = d_in[40];
  (void)ws_size; (void)n_in; (void)in_sizes; (void)out_size;

  // ---- workspace layout (fp32, aliased; ~15.1 MB total) ----
  int* flag = (int*)d_ws;
  float* wsf = (float*)d_ws;
  float* F2  = wsf + 16;              // 393216   : feats_l2 fp32 (3x128x1024)
  float* F1  = F2 + 393216;           // 786432   : feats_l1 fp32 (3x64x4096)
  float* x   = F1 + 786432;           // 393216   : activations (2048x192)
  float* ta  = x + 393216;            // 393216   : LN / hidden buffer
  float* yb  = ta + 393216;           // 393216   : attention out
  float* big = yb + 393216;           // 1572864  : qkv (1.18M) | hid (1.57M) | corrT | decoder scratch
  float* fv  = big + 1572864;         // 4096     : head output (2048x2)
  float* cur = fv + 4096;             // 4096     : [2][2][1024] coarse flow
  float* cur2 = cur + 4096;           // 16384    : [2][2][4096]
  float* corrT = big;                 // 2048x49
  float* qkvb = big;                  // 2048x576
  float* hid  = big;                  // 2048x768 (qkv dead by then)
  float* wp1  = big;                  // [2][128][1024]
  float* mid1 = big + 262144;         // [2][128][1024]
  float* wp0  = big;                  // [2][64][4096]
  float* mid0 = big + 524288;         // [2][64][4096]

  // per-weight dtype-offset helper: byte offset depends on element size, resolved on device
  // via flag, so pass ELEMENT offsets through pointer math done per dtype. We instead pass
  // base pointers + element offsets encoded by advancing char* by offset*size for both cases
  // -> simpler: advance inside ldw-style by passing separate pointers per dtype is overkill;
  // we advance by element count via lambda below computing both candidate pointers is wrong
  // for fp32. So: weights that need sub-indexing get offset applied via ldw index instead.

  k_detect<<<1, 256, 0, stream>>>((const unsigned short*)feats_l1, flag);
  k_cvt<<<1536, 256, 0, stream>>>(feats_l2, F2, 393216, flag);
  k_cvt<<<3072, 256, 0, stream>>>(feats_l1, F1, 786432, flag);

  // ---- tokens (level 1 only) ----
  k_corr<<<dim3(1024, 2), 64, 0, stream>>>(F2, corrT);
  // tok_w[1]: (192x49) at element offset 9408; tok_b[1] at 192. Convert those slices to fp32
  // staging so k_gemm gets a plain base pointer regardless of dtype:
  // reuse tail of `big` region beyond corrT (corrT is 100352 floats) for weight slice staging.
  float* tokw1 = big + 110592;  // 9408 floats
  float* tokb1 = tokw1 + 9408;  // 192 floats
  {
    // stage: need dtype-aware element offset -> do it with two cvt launches using shifted base.
    // k_cvt reads elements [0,n) of src; we need [9408,18816). Launch a dedicated small kernel:
    // easiest: convert the whole tok_w (28224 el) and tok_b (576 el), then point into it.
    float* tokw_all = tokw1;        // 28224 floats
    float* tokb_all = tokw1 + 28224; // 576 floats
    k_cvt<<<111, 256, 0, stream>>>(tok_w_c, tokw_all, 28224, flag);
    k_cvt<<<3, 256, 0, stream>>>(tok_b_c, tokb_all, 576, flag);
    tokw1 = tokw_all + 9408;
    tokb1 = tokb_all + 192;
    k_gemm<0, false><<<dim3(3, 32), 256, 0, stream>>>(corrT, tokw1, tokb1, nullptr,
                                                      x, 2048, 192, 49, flag);
  }

  // helper producing dtype-correct sub-pointer: element offset -> byte offset = off * (isb?2:4).
  // Host doesn't know isb, so instead pass base and let kernels index from base with an element
  // offset baked into the index. k_gemm/k_ln/k_conv index from their pointer argument directly,
  // so we pre-shift byte pointers for BOTH dtype cases... not possible host-side. Solution:
  // stage ALL transformer weights once into fp32 workspace? That needs ~14 MB more. Instead:
  // since all per-block weight slabs are contiguous and blocks are launched separately, we use
  // k_cvt to stage each block's weights into a small fp32 scratch right before its launches.
  float* wstage = big + 140000;  // weight staging region (needs <= 443k floats; big is free here)

  auto tblock = [&](const void* ln1w, long o_ln1w, const void* ln1b, long o_ln1b,
                    const void* inw, long o_inw, const void* inb, long o_inb,
                    const void* ow, long o_ow, const void* ob, long o_ob,
                    const void* ln2w, long o_ln2w, const void* ln2b, long o_ln2b,
                    const void* w1, long o_w1, const void* b1, long o_b1,
                    const void* w2, long o_w2, const void* b2, long o_b2) {
    // stage weights to fp32 (dtype-aware shifted conversion)
    // layout in wstage:
    float* s_ln1w = wstage;            // 192
    float* s_ln1b = s_ln1w + 192;      // 192
    float* s_inw  = s_ln1b + 192;      // 110592
    float* s_inb  = s_inw + 110592;    // 576
    float* s_ow   = s_inb + 576;       // 36864
    float* s_ob   = s_ow + 36864;      // 192
    float* s_ln2w = s_ob + 192;        // 192
    float* s_ln2b = s_ln2w + 192;      // 192
    float* s_w1   = s_ln2b + 192;      // 147456
    float* s_b1   = s_w1 + 147456;     // 768
    float* s_w2   = s_b1 + 768;        // 147456
    float* s_b2   = s_w2 + 147456;     // 192
    // NOTE: staging kernels must apply the ELEMENT offset in a dtype-aware way; k_cvt2 below.
    extern void __nop();
    // use k_cvt_off
    struct L { const void* p; long off; float* dst; int n; };
    L ls[12] = {
      {ln1w, o_ln1w, s_ln1w, 192}, {ln1b, o_ln1b, s_ln1b, 192},
      {inw, o_inw, s_inw, 110592}, {inb, o_inb, s_inb, 576},
      {ow, o_ow, s_ow, 36864}, {ob, o_ob, s_ob, 192},
      {ln2w, o_ln2w, s_ln2w, 192}, {ln2b, o_ln2b, s_ln2b, 192},
      {w1, o_w1, s_w1, 147456}, {b1, o_b1, s_b1, 768},
      {w2, o_w2, s_w2, 147456}, {b2, o_b2, s_b2, 192},
    };
    for (auto& l : ls) {
      extern __global__ void k_cvt_off(const void*, long, float*, int, const int*);
      k_cvt_off<<<(l.n + 255) / 256, 256, 0, stream>>>(l.p, l.off, l.dst, l.n, flag);
    }
    k_ln<<<2048, 64, 0, stream>>>(x, ta, s_ln1w, s_ln1b, flag);  // weights now fp32; but k_ln
    // uses ldw(flag)! For staged fp32 weights we need isb=0 always -> pass zero-flag pointer.
    // (fixed below via zeroflag)
    (void)s_ln1w;
  };
  (void)tblock; // replaced by explicit implementation below (see zeroflag)

  // zero flag constant for staged-fp32 weight consumers
  int* zeroflag = (int*)(wsf + 8);  // within reserved 16-float header
  // set via tiny kernel:
  {
    extern __global__ void k_setzero(int*);
    k_setzero<<<1, 1, 0, stream>>>(zeroflag);
  }

  auto run_block = [&](const void* ln1w, long o1, const void* ln1b, long o2,
                       const void* inw, long o3, const void* inb, long o4,
                       const void* ow, long o5, const void* ob, long o6,
                       const void* ln2w, long o7, const void* ln2b, long o8,
                       const void* w1, long o9, const void* b1, long o10,
                       const void* w2, long o11, const void* b2, long o12) {
    float* s_ln1w = wstage;
    float* s_ln1b = s_ln1w + 192;
    float* s_inw  = s_ln1b + 192;
    float* s_inb  = s_inw + 110592;
    float* s_ow   = s_inb + 576;
    float* s_ob   = s_ow + 36864;
    float* s_ln2w = s_ob + 192;
    float* s_ln2b = s_ln2w + 192;
    float* s_w1   = s_ln2b + 192;
    float* s_b1   = s_w1 + 147456;
    float* s_w2   = s_b1 + 768;
    float* s_b2   = s_w2 + 147456;
    extern __global__ void k_cvt_off(const void*, long, float*, int, const int*);
    k_cvt_off<<<1, 256, 0, stream>>>(ln1w, o1, s_ln1w, 192, flag);
    k_cvt_off<<<1, 256, 0, stream>>>(ln1b, o2, s_ln1b, 192, flag);
    k_cvt_off<<<432, 256, 0, stream>>>(inw, o3, s_inw, 110592, flag);
    k_cvt_off<<<3, 256, 0, stream>>>(inb, o4, s_inb, 576, flag);
    k_cvt_off<<<144, 256, 0, stream>>>(ow, o5, s_ow, 36864, flag);
    k_cvt_off<<<1, 256, 0, stream>>>(ob, o6, s_ob, 192, flag);
    k_cvt_off<<<1, 256, 0, stream>>>(ln2w, o7, s_ln2w, 192, flag);
    k_cvt_off<<<1, 256, 0, stream>>>(ln2b, o8, s_ln2b, 192, flag);
    k_cvt_off<<<576, 256, 0, stream>>>(w1, o9, s_w1, 147456, flag);
    k_cvt_off<<<3, 256, 0, stream>>>(b1, o10, s_b1, 768, flag);
    k_cvt_off<<<576, 256, 0, stream>>>(w2, o11, s_w2, 147456, flag);
    k_cvt_off<<<1, 256, 0, stream>>>(b2, o12, s_b2, 192, flag);

    k_ln<<<2048, 64, 0, stream>>>(x, ta, s_ln1w, s_ln1b, zeroflag);
    k_gemm<0, false><<<dim3(9, 32), 256, 0, stream>>>(ta, s_inw, s_inb, nullptr, qkvb,
                                                      2048, 576, 192, zeroflag);
    k_attn<<<dim3(64, 4, 2), 256, 0, stream>>>(qkvb, yb);
    k_gemm<0, true><<<dim3(3, 32), 256, 0, stream>>>(yb, s_ow, s_ob, x, x,
                                                     2048, 192, 192, zeroflag);
    k_ln<<<2048, 64, 0, stream>>>(x, ta, s_ln2w, s_ln2b, zeroflag);
    k_gemm<1, false><<<dim3(12, 32), 256, 0, stream>>>(ta, s_w1, s_b1, nullptr, hid,
                                                       2048, 768, 192, zeroflag);
    k_gemm<0, true><<<dim3(3, 32), 256, 0, stream>>>(hid, s_w2, s_b2, x, x,
                                                     2048, 192, 768, zeroflag);
  };

  // wstage must not collide with qkvb/hid (both alias `big`!). Move wstage AFTER big region:
  // big is 1572864 floats; hid uses all of it. So place wstage after cur2 instead.
  wstage = cur2 + 16384;   // 443,328 floats (~1.7 MB) -> total ws ~16.9 MB

  // ---- LCM: 6 blocks, both pairs batched ----
  for (int i = 0; i < 6; ++i) {
    run_block(lcm_ln1_w, (long)i * 192, lcm_ln1_b, (long)i * 192,
              lcm_in_w, (long)i * 110592, lcm_in_b, (long)i * 576,
              lcm_out_w, (long)i * 36864, lcm_out_b, (long)i * 192,
              lcm_ln2_w, (long)i * 192, lcm_ln2_b, (long)i * 192,
              lcm_mlp_w1, (long)i * 147456, lcm_mlp_b1, (long)i * 768,
              lcm_mlp_w2, (long)i * 147456, lcm_mlp_b2, (long)i * 192);
  }
  k_ema<<<768, 256, 0, stream>>>(x);

  // ---- GTR: 2 blocks ----
  for (int i = 0; i < 2; ++i) {
    run_block(gtr_ln1_w, (long)i * 192, gtr_ln1_b, (long)i * 192,
              gtr_in_w, (long)i * 110592, gtr_in_b, (long)i * 576,
              gtr_out_w, (long)i * 36864, gtr_out_b, (long)i * 192,
              gtr_ln2_w, (long)i * 192, gtr_ln2_b, (long)i * 192,
              gtr_mlp_w1, (long)i * 147456, gtr_mlp_b1, (long)i * 768,
              gtr_mlp_w2, (long)i * 147456, gtr_mlp_b2, (long)i * 192);
  }

  // ---- head -> coarse flow (weights used directly with dtype flag) ----
  k_gemm<1, false><<<dim3(3, 32), 256, 0, stream>>>(x, head_w1, head_b1, nullptr, ta,
                                                    2048, 192, 192, flag);
  k_gemm<0, false><<<dim3(1, 32), 256, 0, stream>>>(ta, head_w2, head_b2, nullptr, fv,
                                                    2048, 2, 192, flag);
  k_fv2flow<<<16, 256, 0, stream>>>(fv, cur);

  // ---- decoder level 1 (32x32, feats_l2) ----
  for (int it = 0; it < 4; ++it) {
    k_warp<<<1024, 256, 0, stream>>>(F2, cur, wp1, 128, 32, 32);
    k_conv3x3<<<1024, 256, 0, stream>>>(F2, 128, 131072, cur, 2, 2048, wp1, 128, 131072,
                                        ref1_w1, ref1_b1, mid1, 131072, nullptr, 0,
                                        32, 32, 128, 1, flag);
    k_conv3x3<<<16, 256, 0, stream>>>(mid1, 128, 131072, nullptr, 0, 0, nullptr, 0, 0,
                                      ref1_w2, ref1_b2, cur, 2048, cur, 2048,
                                      32, 32, 2, 0, flag);
  }
  k_upsample<<<64, 256, 0, stream>>>(cur, cur2);

  // ---- decoder level 0 (64x64, feats_l1) ----
  for (int it = 0; it < 4; ++it) {
    k_warp<<<2048, 256, 0, stream>>>(F1, cur2, wp0, 64, 64, 64);
    k_conv3x3<<<2048, 256, 0, stream>>>(F1, 64, 262144, cur2, 2, 8192, wp0, 64, 262144,
                                        ref0_w1, ref0_b1, mid0, 262144, nullptr, 0,
                                        64, 64, 64, 1, flag);
    k_conv3x3<<<64, 256, 0, stream>>>(mid0, 64, 262144, nullptr, 0, 0, nullptr, 0, 0,
                                      ref0_w2, ref0_b2, cur2, 8192, cur2, 8192,
                                      64, 64, 2, 0, flag);
  }

  k_out<<<64, 256, 0, stream>>>(cur2, d_out, flag);
}

// dtype-aware shifted conversion: dst[i] = src[off + i] (src is bf16 or fp32 per *fl)
__global__ void k_cvt_off(const void* __restrict__ s, long off, float* __restrict__ d,
                          int n, const int* __restrict__ fl) {
  int isb = *fl;
  int i = blockIdx.x * blockDim.x + threadIdx.x;
  if (i < n) d[i] = ldw(s, off + i, isb);
}

__global__ void k_setzero(int* p) { *p = 0; }

// Round 3
// 4773.698 us; speedup vs baseline: 1.5099x; 1.5099x over previous
//
#include <hip/hip_runtime.h>
#include <hip/hip_bf16.h>

typedef __hip_bfloat16 bf16;

#define DEV __device__ __forceinline__

DEV float bf2f(bf16 v) { return __bfloat162float(v); }
DEV bf16 f2bf(float v) { return __float2bfloat16(v); }
DEV float gelu_exact(float x) { return 0.5f * x * (1.0f + erff(x * 0.70710678118654752f)); }

// load a "reference float32" parameter that may physically be bf16 or fp32
DEV float ldw(const void* p, long i, int isb) {
  return isb ? __bfloat162float(((const bf16*)p)[i]) : ((const float*)p)[i];
}

// ---------------- dtype detection ----------------
__global__ void k_detect(const unsigned short* __restrict__ u, int* __restrict__ flag) {
  __shared__ int bad;
  if (threadIdx.x == 0) bad = 0;
  __syncthreads();
  for (int i = threadIdx.x; i < 8192; i += 256) {
    int expo = (u[i] >> 7) & 0xFF;
    if (expo >= 138) atomicOr(&bad, 1);
  }
  __syncthreads();
  if (threadIdx.x == 0) *flag = bad ? 0 : 1;
}

// ---------------- convert (bf16|fp32) -> fp32 ----------------
__global__ void k_cvt(const void* __restrict__ s, float* __restrict__ d, int n,
                      const int* __restrict__ fl) {
  int isb = *fl;
  int i = blockIdx.x * blockDim.x + threadIdx.x;
  if (i < n) d[i] = ldw(s, i, isb);
}

// ---------------- local correlation (level 1), output stride 64 (zero-padded) -------------
__global__ void k_corr(const float* __restrict__ F2, float* __restrict__ corrT) {
  __shared__ float f1v[128];
  int p = blockIdx.x;          // pixel 0..1023
  int b = blockIdx.y;          // pair 0..1
  int t = threadIdx.x;         // 64 threads
  const float* f1 = F2 + (long)b * 131072;
  const float* f2 = F2 + (long)(b + 1) * 131072;
  f1v[t]      = f1[t * 1024 + p];
  f1v[t + 64] = f1[(t + 64) * 1024 + p];
  __syncthreads();
  long rowo = ((long)b * 1024 + p) * 64;
  if (t < 49) {
    int dy = t / 7 - 3, dx = t % 7 - 3;
    int h = p >> 5, w = p & 31;
    int p2 = (((h - dy) & 31) << 5) | ((w - dx) & 31);
    float s = 0.0f;
    for (int c = 0; c < 128; ++c) s += f1v[c] * f2[c * 1024 + p2];
    corrT[rowo + t] = s * 0.08838834764831845f; // 1/sqrt(128)
  } else {
    corrT[rowo + t] = 0.0f;
  }
}

// ---------------- LayerNorm (D=192), one wave per row, direct weights ----------------
__global__ void k_ln(const float* __restrict__ src, float* __restrict__ dst,
                     const void* __restrict__ w, long woff,
                     const void* __restrict__ b, long boff,
                     const int* __restrict__ fl) {
  int isb = *fl;
  int row = blockIdx.x;
  int t = threadIdx.x; // 64
  const float* s = src + (long)row * 192;
  float e0 = s[t], e1 = s[t + 64], e2 = s[t + 128];
  float sum = e0 + e1 + e2;
  for (int o = 32; o; o >>= 1) sum += __shfl_xor(sum, o);
  float mean = sum * (1.0f / 192.0f);
  float d0 = e0 - mean, d1 = e1 - mean, d2 = e2 - mean;
  float vs = d0 * d0 + d1 * d1 + d2 * d2;
  for (int o = 32; o; o >>= 1) vs += __shfl_xor(vs, o);
  float rstd = rsqrtf(vs * (1.0f / 192.0f) + 1e-5f);
  float* o_ = dst + (long)row * 192;
  o_[t]       = d0 * rstd * ldw(w, woff + t, isb)       + ldw(b, boff + t, isb);
  o_[t + 64]  = d1 * rstd * ldw(w, woff + t + 64, isb)  + ldw(b, boff + t + 64, isb);
  o_[t + 128] = d2 * rstd * ldw(w, woff + t + 128, isb) + ldw(b, boff + t + 128, isb);
}

// ---------------- GEMM: C(MxN) = A(MxK) @ W(NxKw)^T + bias (+res) (+gelu) ----------------
// BM=128, BN=64, BK=16, 256 threads, 8x4 microtile, float4 LDS reads.
// Requires: M % 128 == 0, K % 16 == 0 (A may be zero-padded to K >= Kw; W rows are Kw wide).
template <int ACT, bool HASRES>
__global__ __launch_bounds__(256) void k_gemm(const float* __restrict__ A,
                                              const void* __restrict__ W, long woff,
                                              const void* __restrict__ bias, long boff,
                                              const float* __restrict__ res,
                                              float* __restrict__ C, int M, int N, int K, int Kw,
                                              const int* __restrict__ fl) {
  int isb = *fl;
  __shared__ float As[16][132];
  __shared__ float Ws[16][68];
  int tid = threadIdx.x;
  int tx = tid & 15, ty = tid >> 4;
  int m0 = blockIdx.y * 128, n0 = blockIdx.x * 64;
  float acc[8][4] = {};
  for (int k0 = 0; k0 < K; k0 += 16) {
#pragma unroll
    for (int i = 0; i < 2; ++i) {
      int idx4 = tid + i * 256;           // 512 float4 units = 128x16 tile
      int mm = idx4 >> 2, kc = (idx4 & 3) * 4;
      float4 v = *(const float4*)(A + (long)(m0 + mm) * K + k0 + kc);
      As[kc][mm] = v.x; As[kc + 1][mm] = v.y; As[kc + 2][mm] = v.z; As[kc + 3][mm] = v.w;
    }
#pragma unroll
    for (int i = 0; i < 4; ++i) {
      int idx = tid + i * 256;            // 1024 elements = 64x16 tile
      int nn = idx >> 4, kk = idx & 15;
      int gn = n0 + nn, gk = k0 + kk;
      Ws[kk][nn] = (gn < N && gk < Kw) ? ldw(W, woff + (long)gn * Kw + gk, isb) : 0.0f;
    }
    __syncthreads();
#pragma unroll
    for (int kk = 0; kk < 16; ++kk) {
      float4 a0 = *(const float4*)&As[kk][ty * 8];
      float4 a1 = *(const float4*)&As[kk][ty * 8 + 4];
      float4 w4 = *(const float4*)&Ws[kk][tx * 4];
      float av[8] = {a0.x, a0.y, a0.z, a0.w, a1.x, a1.y, a1.z, a1.w};
      float wv[4] = {w4.x, w4.y, w4.z, w4.w};
#pragma unroll
      for (int i = 0; i < 8; ++i)
#pragma unroll
        for (int j = 0; j < 4; ++j) acc[i][j] += av[i] * wv[j];
    }
    __syncthreads();
  }
#pragma unroll
  for (int i = 0; i < 8; ++i) {
    int gm = m0 + ty * 8 + i;
#pragma unroll
    for (int j = 0; j < 4; ++j) {
      int gn = n0 + tx * 4 + j;
      if (gn >= N) continue;
      float v = acc[i][j] + ldw(bias, boff + gn, isb);
      if (HASRES) v += res[(long)gm * N + gn];
      if (ACT == 1) v = gelu_exact(v);
      C[(long)gm * N + gn] = v;
    }
  }
}

// ---------------- fused attention (flash, Br=16, Bc=64), heads=4, HD=48, N=1024/pair --------
__global__ __launch_bounds__(256) void k_attn(const float* __restrict__ qkv, float* __restrict__ y) {
  __shared__ float Qs[16][52];
  __shared__ float Ks[64][52];
  __shared__ float Vs[64][52];
  __shared__ float S[16][68];
  __shared__ float mS[16], lS[16], aS[16];
  int tid = threadIdx.x;
  int h = blockIdx.y, b = blockIdx.z;
  int q0 = blockIdx.x * 16;
  const float* base = qkv + (long)b * 1024 * 576;
  const float SC = 0.14433756729740643f; // 1/sqrt(48)
  for (int i = tid; i < 192; i += 256) {  // 16 rows x 12 chunks
    int r = i / 12, ch = i % 12;
    float4 v = *(const float4*)(base + (long)(q0 + r) * 576 + h * 48 + ch * 4);
    v.x *= SC; v.y *= SC; v.z *= SC; v.w *= SC;
    *(float4*)&Qs[r][ch * 4] = v;
  }
  if (tid < 16) { mS[tid] = -1e30f; lS[tid] = 0.0f; }
  int pr = tid / 12, pch = tid % 12;  // PV ownership (tid < 192)
  float4 o = {0.0f, 0.0f, 0.0f, 0.0f};
  __syncthreads();
  for (int kc = 0; kc < 16; ++kc) {
    int k0 = kc * 64;
    for (int i = tid; i < 768; i += 256) {  // 64 rows x 12 chunks
      int r = i / 12, ch = i % 12;
      *(float4*)&Ks[r][ch * 4] =
          *(const float4*)(base + (long)(k0 + r) * 576 + 192 + h * 48 + ch * 4);
      *(float4*)&Vs[r][ch * 4] =
          *(const float4*)(base + (long)(k0 + r) * 576 + 384 + h * 48 + ch * 4);
    }
    __syncthreads();
    {
      int c = tid & 63, rb = tid >> 6;  // rows rb, rb+4, rb+8, rb+12
      float s0 = 0, s1 = 0, s2 = 0, s3 = 0;
#pragma unroll
      for (int ch = 0; ch < 12; ++ch) {
        float4 k4 = *(const float4*)&Ks[c][ch * 4];
        float4 q;
        q = *(const float4*)&Qs[rb][ch * 4];
        s0 += q.x * k4.x + q.y * k4.y + q.z * k4.z + q.w * k4.w;
        q = *(const float4*)&Qs[rb + 4][ch * 4];
        s1 += q.x * k4.x + q.y * k4.y + q.z * k4.z + q.w * k4.w;
        q = *(const float4*)&Qs[rb + 8][ch * 4];
        s2 += q.x * k4.x + q.y * k4.y + q.z * k4.z + q.w * k4.w;
        q = *(const float4*)&Qs[rb + 12][ch * 4];
        s3 += q.x * k4.x + q.y * k4.y + q.z * k4.z + q.w * k4.w;
      }
      S[rb][c] = s0; S[rb + 4][c] = s1; S[rb + 8][c] = s2; S[rb + 12][c] = s3;
    }
    __syncthreads();
    {
      int g = tid >> 4, l = tid & 15;
      float v0 = S[g][l], v1 = S[g][l + 16], v2 = S[g][l + 32], v3 = S[g][l + 48];
      float mx = fmaxf(fmaxf(v0, v1), fmaxf(v2, v3));
      for (int o2 = 8; o2; o2 >>= 1) mx = fmaxf(mx, __shfl_xor(mx, o2, 16));
      float mOld = mS[g];
      mx = fmaxf(mx, mOld);
      float p0 = __expf(v0 - mx), p1 = __expf(v1 - mx), p2 = __expf(v2 - mx), p3 = __expf(v3 - mx);
      S[g][l] = p0; S[g][l + 16] = p1; S[g][l + 32] = p2; S[g][l + 48] = p3;
      float sum = p0 + p1 + p2 + p3;
      for (int o2 = 8; o2; o2 >>= 1) sum += __shfl_xor(sum, o2, 16);
      if (l == 0) {
        float alpha = __expf(mOld - mx);
        aS[g] = alpha;
        lS[g] = lS[g] * alpha + sum;
        mS[g] = mx;
      }
    }
    __syncthreads();
    if (tid < 192) {
      float a = aS[pr];
      o.x *= a; o.y *= a; o.z *= a; o.w *= a;
#pragma unroll
      for (int c4 = 0; c4 < 16; ++c4) {
        float4 s4 = *(const float4*)&S[pr][c4 * 4];
        float4 v;
        v = *(const float4*)&Vs[c4 * 4 + 0][pch * 4];
        o.x += s4.x * v.x; o.y += s4.x * v.y; o.z += s4.x * v.z; o.w += s4.x * v.w;
        v = *(const float4*)&Vs[c4 * 4 + 1][pch * 4];
        o.x += s4.y * v.x; o.y += s4.y * v.y; o.z += s4.y * v.z; o.w += s4.y * v.w;
        v = *(const float4*)&Vs[c4 * 4 + 2][pch * 4];
        o.x += s4.z * v.x; o.y += s4.z * v.y; o.z += s4.z * v.z; o.w += s4.z * v.w;
        v = *(const float4*)&Vs[c4 * 4 + 3][pch * 4];
        o.x += s4.w * v.x; o.y += s4.w * v.y; o.z += s4.w * v.z; o.w += s4.w * v.w;
      }
    }
    __syncthreads();
  }
  if (tid < 192) {
    float inv = 1.0f / lS[pr];
    o.x *= inv; o.y *= inv; o.z *= inv; o.w *= inv;
    *(float4*)(y + (long)b * 1024 * 192 + (long)(q0 + pr) * 192 + h * 48 + pch * 4) = o;
  }
}

// ---------------- EMA: x[pair1] = 0.8*x[pair1] + 0.2*x[pair0] ----------------
__global__ void k_ema(float* __restrict__ x) {
  int i = blockIdx.x * blockDim.x + threadIdx.x;
  if (i < 196608) x[196608 + i] = 0.8f * x[196608 + i] + 0.2f * x[i];
}

// ---------------- fv (2048x2) -> flow [b][2][1024] ----------------
__global__ void k_fv2flow(const float* __restrict__ fv, float* __restrict__ cur) {
  int i = blockIdx.x * blockDim.x + threadIdx.x;
  if (i < 4096) {
    int b = i >> 11, r = i & 2047;
    int c = r >> 10, p = r & 1023;
    cur[i] = fv[(long)(b * 1024 + p) * 2 + c];
  }
}

// ---------------- warp (bilinear, border clamp); img for pair b is imgbase[(b+1)] --------
__global__ void k_warp(const float* __restrict__ imgbase, const float* __restrict__ flow,
                       float* __restrict__ out, int C, int H, int W) {
  int HW = H * W;
  int per = C * HW;
  int i = blockIdx.x * blockDim.x + threadIdx.x;
  if (i >= 2 * per) return;
  int b = i / per;
  int rem = i - b * per;
  int c = rem / HW;
  int p = rem - c * HW;
  int h = p / W, w = p - h * W;
  const float* img = imgbase + (long)(b + 1) * per;
  const float* fl = flow + (long)b * 2 * HW;
  float x = fminf(fmaxf((float)w + fl[p], 0.0f), (float)(W - 1));
  float yy = fminf(fmaxf((float)h + fl[HW + p], 0.0f), (float)(H - 1));
  int x0 = (int)floorf(x), y0 = (int)floorf(yy);
  int x1 = min(x0 + 1, W - 1), y1 = min(y0 + 1, H - 1);
  float wx = x - (float)x0, wy = yy - (float)y0;
  const float* ic = img + (long)c * HW;
  float v00 = ic[y0 * W + x0], v01 = ic[y0 * W + x1];
  float v10 = ic[y1 * W + x0], v11 = ic[y1 * W + x1];
  out[i] = v00 * (1 - wx) * (1 - wy) + v01 * wx * (1 - wy) + v10 * (1 - wx) * wy + v11 * wx * wy;
}

// ---------------- LDS-tiled 3x3 conv (zero pad), 3-segment concat input, batched pairs ----
// 16x16 spatial tile per block, OCG output channels per thread, 4-channel LDS batches.
// Weights pre-converted to fp32 (uniform-index scalar loads).
template <int OCG>
__global__ __launch_bounds__(256) void k_conv3x3(
    const float* __restrict__ s0, int c0, long s0bs,
    const float* __restrict__ s1, int c1, long s1bs,
    const float* __restrict__ s2, int c2, long s2bs,
    const float* __restrict__ wgt, const float* __restrict__ bias,
    float* __restrict__ out, long outbs,
    const float* __restrict__ res, long resbs,
    int H, int W, int act) {
  __shared__ float T[4][18][20];
  int tid = threadIdx.x;
  int nTx = W >> 4;
  int tileId = blockIdx.x;
  int ty0 = (tileId / nTx) << 4, tx0 = (tileId % nTx) << 4;
  int oc0 = blockIdx.y * OCG;
  int b = blockIdx.z;
  int ly = tid >> 4, lx = tid & 15;
  int gy = ty0 + ly, gx = tx0 + lx;
  int ICT = c0 + c1 + c2;
  float acc[OCG];
#pragma unroll
  for (int o = 0; o < OCG; ++o) acc[o] = bias[oc0 + o];
  const float* segp[3] = { s0 + (long)b * s0bs,
                           s1 ? s1 + (long)b * s1bs : nullptr,
                           s2 ? s2 + (long)b * s2bs : nullptr };
  int segc[3] = { c0, c1, c2 };
  int icb = 0;
  for (int sg = 0; sg < 3; ++sg) {
    const float* sp = segp[sg];
    int cc = segc[sg];
    for (int ic0 = 0; ic0 < cc; ic0 += 4) {
      int nb = min(4, cc - ic0);
      for (int i = tid; i < nb * 324; i += 256) {
        int bch = i / 324, w2 = i % 324;
        int rr = w2 / 18, c2i = w2 % 18;
        int yy = ty0 - 1 + rr, xx = tx0 - 1 + c2i;
        float v = (yy >= 0 && yy < H && xx >= 0 && xx < W)
                      ? sp[(long)(ic0 + bch) * H * W + yy * W + xx] : 0.0f;
        T[bch][rr][c2i] = v;
      }
      __syncthreads();
      for (int j = 0; j < nb; ++j) {
        float t00 = T[j][ly][lx],     t01 = T[j][ly][lx + 1],     t02 = T[j][ly][lx + 2];
        float t10 = T[j][ly + 1][lx], t11 = T[j][ly + 1][lx + 1], t12 = T[j][ly + 1][lx + 2];
        float t20 = T[j][ly + 2][lx], t21 = T[j][ly + 2][lx + 1], t22 = T[j][ly + 2][lx + 2];
        long wb = ((long)oc0 * ICT + (icb + ic0 + j)) * 9;
#pragma unroll
        for (int o = 0; o < OCG; ++o) {
          const float* wp = wgt + wb + (long)o * ICT * 9;
          acc[o] += t00 * wp[0] + t01 * wp[1] + t02 * wp[2]
                  + t10 * wp[3] + t11 * wp[4] + t12 * wp[5]
                  + t20 * wp[6] + t21 * wp[7] + t22 * wp[8];
        }
      }
      __syncthreads();
    }
    icb += cc;
  }
  long p = (long)gy * W + gx;
#pragma unroll
  for (int o = 0; o < OCG; ++o) {
    float v = acc[o];
    if (act) v = gelu_exact(v);
    if (res) v += res[(long)b * resbs + (long)(oc0 + o) * H * W + p];
    out[(long)b * outbs + (long)(oc0 + o) * H * W + p] = v;
  }
}

// ---------------- 2x align-corners bilinear upsample (2x2x32x32 -> 2x2x64x64) -------------
__global__ void k_upsample(const float* __restrict__ in, float* __restrict__ out) {
  int i = blockIdx.x * blockDim.x + threadIdx.x;
  if (i >= 2 * 2 * 64 * 64) return;
  int p = i & 4095;
  int bc = i >> 12;
  int oy = p >> 6, ox = p & 63;
  float sx = ox * (31.0f / 63.0f), sy = oy * (31.0f / 63.0f);
  int x0 = (int)sx, y0 = (int)sy;
  int x1 = min(x0 + 1, 31), y1 = min(y0 + 1, 31);
  float wx = sx - x0, wy = sy - y0;
  const float* ic = in + (long)bc * 1024;
  out[i] = ic[y0 * 32 + x0] * (1 - wx) * (1 - wy) + ic[y0 * 32 + x1] * wx * (1 - wy)
         + ic[y1 * 32 + x0] * (1 - wx) * wy      + ic[y1 * 32 + x1] * wx * wy;
}

// ---------------- final write (fp32 -> bf16|fp32 per detected dtype) ----------------
__global__ void k_out(const float* __restrict__ cur2, void* __restrict__ out,
                      const int* __restrict__ fl) {
  int isb = *fl;
  int i = blockIdx.x * blockDim.x + threadIdx.x;
  if (i < 16384) {
    if (isb) ((bf16*)out)[i] = f2bf(cur2[i]);
    else ((float*)out)[i] = cur2[i];
  }
}

extern "C" void kernel_launch(void* const* d_in, const int* in_sizes, int n_in,
                              void* d_out, int out_size, void* d_ws, size_t ws_size,
                              hipStream_t stream) {
  const void* feats_l1 = d_in[0];
  const void* feats_l2 = d_in[1];
  const void* tok_w = d_in[3];
  const void* tok_b = d_in[4];
  const void* lcm_ln1_w = d_in[5];
  const void* lcm_ln1_b = d_in[6];
  const void* lcm_in_w  = d_in[7];
  const void* lcm_in_b  = d_in[8];
  const void* lcm_out_w = d_in[9];
  const void* lcm_out_b = d_in[10];
  const void* lcm_ln2_w = d_in[11];
  const void* lcm_ln2_b = d_in[12];
  const void* lcm_mlp_w1 = d_in[13];
  const void* lcm_mlp_b1 = d_in[14];
  const void* lcm_mlp_w2 = d_in[15];
  const void* lcm_mlp_b2 = d_in[16];
  const void* gtr_ln1_w = d_in[17];
  const void* gtr_ln1_b = d_in[18];
  const void* gtr_in_w  = d_in[19];
  const void* gtr_in_b  = d_in[20];
  const void* gtr_out_w = d_in[21];
  const void* gtr_out_b = d_in[22];
  const void* gtr_ln2_w = d_in[23];
  const void* gtr_ln2_b = d_in[24];
  const void* gtr_mlp_w1 = d_in[25];
  const void* gtr_mlp_b1 = d_in[26];
  const void* gtr_mlp_w2 = d_in[27];
  const void* gtr_mlp_b2 = d_in[28];
  const void* head_w1 = d_in[29];
  const void* head_b1 = d_in[30];
  const void* head_w2 = d_in[31];
  const void* head_b2 = d_in[32];
  const void* ref1_w1 = d_in[33];
  const void* ref1_b1 = d_in[34];
  const void* ref1_w2 = d_in[35];
  const void* ref1_b2 = d_in[36];
  const void* ref0_w1 = d_in[37];
  const void* ref0_b1 = d_in[38];
  const void* ref0_w2 = d_in[39];
  const void* ref0_b2 = d_in[40];
  (void)ws_size; (void)n_in; (void)in_sizes; (void)out_size;

  // ---- workspace layout (fp32; ~17.3 MB) ----
  int* flag = (int*)d_ws;
  float* wsf = (float*)d_ws;
  float* F2  = wsf + 16;              // 393216
  float* F1  = F2 + 393216;           // 786432
  float* x   = F1 + 786432;           // 393216
  float* ta  = x + 393216;            // 393216
  float* yb  = ta + 393216;           // 393216
  float* big = yb + 393216;           // 1572864: corrT | qkvb | hid | decoder scratch
  float* fv  = big + 1572864;         // 4096
  float* cur = fv + 4096;             // 4096   [2][2][1024]
  float* cur2 = cur + 4096;           // 16384  [2][2][4096]
  float* cw1a = cur2 + 16384;         // 297216 : ref1_w1 fp32
  float* cb1a = cw1a + 297216;        // 128
  float* cw1b = cb1a + 128;           // 2304
  float* cb1b = cw1b + 2304;          // 16 (2 used)
  float* cw0a = cb1b + 16;            // 74880
  float* cb0a = cw0a + 74880;         // 64
  float* cw0b = cb0a + 64;            // 1152
  float* cb0b = cw0b + 1152;          // 16 (2 used)
  float* corrT = big;                 // 2048 x 64 (zero-padded K)
  float* qkvb = big;                  // 2048 x 576
  float* hid  = big;                  // 2048 x 768
  float* wp1  = big;                  // [2][128][1024]
  float* mid1 = big + 262144;         // [2][128][1024]
  float* wp0  = big;                  // [2][64][4096]
  float* mid0 = big + 524288;         // [2][64][4096]

  k_detect<<<1, 256, 0, stream>>>((const unsigned short*)feats_l1, flag);
  k_cvt<<<1536, 256, 0, stream>>>(feats_l2, F2, 393216, flag);
  k_cvt<<<3072, 256, 0, stream>>>(feats_l1, F1, 786432, flag);
  // conv weights -> fp32 once (enables scalar/uniform weight loads in k_conv3x3)
  k_cvt<<<1161, 256, 0, stream>>>(ref1_w1, cw1a, 297216, flag);
  k_cvt<<<1, 256, 0, stream>>>(ref1_b1, cb1a, 128, flag);
  k_cvt<<<9, 256, 0, stream>>>(ref1_w2, cw1b, 2304, flag);
  k_cvt<<<1, 256, 0, stream>>>(ref1_b2, cb1b, 2, flag);
  k_cvt<<<293, 256, 0, stream>>>(ref0_w1, cw0a, 74880, flag);
  k_cvt<<<1, 256, 0, stream>>>(ref0_b1, cb0a, 64, flag);
  k_cvt<<<5, 256, 0, stream>>>(ref0_w2, cw0b, 1152, flag);
  k_cvt<<<1, 256, 0, stream>>>(ref0_b2, cb0b, 2, flag);

  // ---- tokens (level 1 only): corr (K padded to 64) then tokenizer GEMM ----
  k_corr<<<dim3(1024, 2), 64, 0, stream>>>(F2, corrT);
  // tok_w[1] at element offset 9408 (192x49); tok_b[1] at 192
  k_gemm<0, false><<<dim3(3, 16), 256, 0, stream>>>(corrT, tok_w, 9408, tok_b, 192, nullptr,
                                                    x, 2048, 192, 64, 49, flag);

  auto run_block = [&](const void* ln1w, long o1, const void* ln1b, long o2,
                       const void* inw, long o3, const void* inb, long o4,
                       const void* ow, long o5, const void* ob, long o6,
                       const void* ln2w, long o7, const void* ln2b, long o8,
                       const void* w1, long o9, const void* b1, long o10,
                       const void* w2, long o11, const void* b2, long o12) {
    k_ln<<<2048, 64, 0, stream>>>(x, ta, ln1w, o1, ln1b, o2, flag);
    k_gemm<0, false><<<dim3(9, 16), 256, 0, stream>>>(ta, inw, o3, inb, o4, nullptr, qkvb,
                                                      2048, 576, 192, 192, flag);
    k_attn<<<dim3(64, 4, 2), 256, 0, stream>>>(qkvb, yb);
    k_gemm<0, true><<<dim3(3, 16), 256, 0, stream>>>(yb, ow, o5, ob, o6, x, x,
                                                     2048, 192, 192, 192, flag);
    k_ln<<<2048, 64, 0, stream>>>(x, ta, ln2w, o7, ln2b, o8, flag);
    k_gemm<1, false><<<dim3(12, 16), 256, 0, stream>>>(ta, w1, o9, b1, o10, nullptr, hid,
                                                       2048, 768, 192, 192, flag);
    k_gemm<0, true><<<dim3(3, 16), 256, 0, stream>>>(hid, w2, o11, b2, o12, x, x,
                                                     2048, 192, 768, 768, flag);
  };

  // ---- LCM: 6 blocks, both pairs batched (rows 0..1023 = pair0, 1024..2047 = pair1) ----
  for (int i = 0; i < 6; ++i) {
    run_block(lcm_ln1_w, (long)i * 192, lcm_ln1_b, (long)i * 192,
              lcm_in_w, (long)i * 110592, lcm_in_b, (long)i * 576,
              lcm_out_w, (long)i * 36864, lcm_out_b, (long)i * 192,
              lcm_ln2_w, (long)i * 192, lcm_ln2_b, (long)i * 192,
              lcm_mlp_w1, (long)i * 147456, lcm_mlp_b1, (long)i * 768,
              lcm_mlp_w2, (long)i * 147456, lcm_mlp_b2, (long)i * 192);
  }
  k_ema<<<768, 256, 0, stream>>>(x);

  // ---- GTR: 2 blocks ----
  for (int i = 0; i < 2; ++i) {
    run_block(gtr_ln1_w, (long)i * 192, gtr_ln1_b, (long)i * 192,
              gtr_in_w, (long)i * 110592, gtr_in_b, (long)i * 576,
              gtr_out_w, (long)i * 36864, gtr_out_b, (long)i * 192,
              gtr_ln2_w, (long)i * 192, gtr_ln2_b, (long)i * 192,
              gtr_mlp_w1, (long)i * 147456, gtr_mlp_b1, (long)i * 768,
              gtr_mlp_w2, (long)i * 147456, gtr_mlp_b2, (long)i * 192);
  }

  // ---- head -> coarse flow ----
  k_gemm<1, false><<<dim3(3, 16), 256, 0, stream>>>(x, head_w1, 0, head_b1, 0, nullptr, ta,
                                                    2048, 192, 192, 192, flag);
  k_gemm<0, false><<<dim3(1, 16), 256, 0, stream>>>(ta, head_w2, 0, head_b2, 0, nullptr, fv,
                                                    2048, 2, 192, 192, flag);
  k_fv2flow<<<16, 256, 0, stream>>>(fv, cur);

  // ---- decoder level 1 (32x32, feats_l2) ----
  for (int it = 0; it < 4; ++it) {
    k_warp<<<1024, 256, 0, stream>>>(F2, cur, wp1, 128, 32, 32);
    k_conv3x3<8><<<dim3(4, 16, 2), 256, 0, stream>>>(
        F2, 128, 131072, cur, 2, 2048, wp1, 128, 131072,
        cw1a, cb1a, mid1, 131072, nullptr, 0, 32, 32, 1);
    k_conv3x3<2><<<dim3(4, 1, 2), 256, 0, stream>>>(
        mid1, 128, 131072, nullptr, 0, 0, nullptr, 0, 0,
        cw1b, cb1b, cur, 2048, cur, 2048, 32, 32, 0);
  }
  k_upsample<<<64, 256, 0, stream>>>(cur, cur2);

  // ---- decoder level 0 (64x64, feats_l1) ----
  for (int it = 0; it < 4; ++it) {
    k_warp<<<2048, 256, 0, stream>>>(F1, cur2, wp0, 64, 64, 64);
    k_conv3x3<8><<<dim3(16, 8, 2), 256, 0, stream>>>(
        F1, 64, 262144, cur2, 2, 8192, wp0, 64, 262144,
        cw0a, cb0a, mid0, 262144, nullptr, 0, 64, 64, 1);
    k_conv3x3<2><<<dim3(16, 1, 2), 256, 0, stream>>>(
        mid0, 64, 262144, nullptr, 0, 0, nullptr, 0, 0,
        cw0b, cb0b, cur2, 8192, cur2, 8192, 64, 64, 0);
  }

  k_out<<<64, 256, 0, stream>>>(cur2, d_out, flag);
}

// Round 4
// 3174.846 us; speedup vs baseline: 2.2703x; 1.5036x over previous
//
#include <hip/hip_runtime.h>
#include <hip/hip_bf16.h>

typedef __hip_bfloat16 bf16;

#define DEV __device__ __forceinline__

DEV float bf2f(bf16 v) { return __bfloat162float(v); }
DEV bf16 f2bf(float v) { return __float2bfloat16(v); }
DEV float gelu_exact(float x) { return 0.5f * x * (1.0f + erff(x * 0.70710678118654752f)); }

// load a "reference float32" parameter that may physically be bf16 or fp32
DEV float ldw(const void* p, long i, int isb) {
  return isb ? __bfloat162float(((const bf16*)p)[i]) : ((const float*)p)[i];
}

// ---------------- dtype detection ----------------
__global__ void k_detect(const unsigned short* __restrict__ u, int* __restrict__ flag) {
  __shared__ int bad;
  if (threadIdx.x == 0) bad = 0;
  __syncthreads();
  for (int i = threadIdx.x; i < 8192; i += 256) {
    int expo = (u[i] >> 7) & 0xFF;
    if (expo >= 138) atomicOr(&bad, 1);
  }
  __syncthreads();
  if (threadIdx.x == 0) *flag = bad ? 0 : 1;
}

// ---------------- convert (bf16|fp32) -> fp32 ----------------
__global__ void k_cvt(const void* __restrict__ s, float* __restrict__ d, int n,
                      const int* __restrict__ fl) {
  int isb = *fl;
  int i = blockIdx.x * blockDim.x + threadIdx.x;
  if (i < n) d[i] = ldw(s, i, isb);
}

// convert + transpose conv weights [OC][ICT][9] -> fp32 [ICT][OC][9]
__global__ void k_cvt_trans(const void* __restrict__ s, float* __restrict__ d,
                            int OC, int ICT, int n, const int* __restrict__ fl) {
  int isb = *fl;
  int i = blockIdx.x * blockDim.x + threadIdx.x;
  if (i >= n) return;
  int oc = i / (ICT * 9);
  int r = i - oc * ICT * 9;
  int ic = r / 9, k = r - ic * 9;
  d[((long)ic * OC + oc) * 9 + k] = ldw(s, i, isb);
}

// ---------------- local correlation (level 1), output stride 64 (zero-padded) -------------
__global__ void k_corr(const float* __restrict__ F2, float* __restrict__ corrT) {
  __shared__ float f1v[128];
  int p = blockIdx.x;          // pixel 0..1023
  int b = blockIdx.y;          // pair 0..1
  int t = threadIdx.x;         // 64 threads
  const float* f1 = F2 + (long)b * 131072;
  const float* f2 = F2 + (long)(b + 1) * 131072;
  f1v[t]      = f1[t * 1024 + p];
  f1v[t + 64] = f1[(t + 64) * 1024 + p];
  __syncthreads();
  long rowo = ((long)b * 1024 + p) * 64;
  if (t < 49) {
    int dy = t / 7 - 3, dx = t % 7 - 3;
    int h = p >> 5, w = p & 31;
    int p2 = (((h - dy) & 31) << 5) | ((w - dx) & 31);
    float s = 0.0f;
    for (int c = 0; c < 128; ++c) s += f1v[c] * f2[c * 1024 + p2];
    corrT[rowo + t] = s * 0.08838834764831845f; // 1/sqrt(128)
  } else {
    corrT[rowo + t] = 0.0f;
  }
}

// ---------------- LayerNorm (D=192), one wave per row, direct weights ----------------
__global__ void k_ln(const float* __restrict__ src, float* __restrict__ dst,
                     const void* __restrict__ w, long woff,
                     const void* __restrict__ b, long boff,
                     const int* __restrict__ fl) {
  int isb = *fl;
  int row = blockIdx.x;
  int t = threadIdx.x; // 64
  const float* s = src + (long)row * 192;
  float e0 = s[t], e1 = s[t + 64], e2 = s[t + 128];
  float sum = e0 + e1 + e2;
  for (int o = 32; o; o >>= 1) sum += __shfl_xor(sum, o);
  float mean = sum * (1.0f / 192.0f);
  float d0 = e0 - mean, d1 = e1 - mean, d2 = e2 - mean;
  float vs = d0 * d0 + d1 * d1 + d2 * d2;
  for (int o = 32; o; o >>= 1) vs += __shfl_xor(vs, o);
  float rstd = rsqrtf(vs * (1.0f / 192.0f) + 1e-5f);
  float* o_ = dst + (long)row * 192;
  o_[t]       = d0 * rstd * ldw(w, woff + t, isb)       + ldw(b, boff + t, isb);
  o_[t + 64]  = d1 * rstd * ldw(w, woff + t + 64, isb)  + ldw(b, boff + t + 64, isb);
  o_[t + 128] = d2 * rstd * ldw(w, woff + t + 128, isb) + ldw(b, boff + t + 128, isb);
}

// ---------------- GEMM: C(MxN) = A(MxK) @ W(NxKw)^T + bias (+res) (+gelu) ----------------
// BM=128, BN=64, BK=16, 256 threads, 8x4 microtile, float4 LDS reads.
template <int ACT, bool HASRES>
__global__ __launch_bounds__(256) void k_gemm(const float* __restrict__ A,
                                              const void* __restrict__ W, long woff,
                                              const void* __restrict__ bias, long boff,
                                              const float* __restrict__ res,
                                              float* __restrict__ C, int M, int N, int K, int Kw,
                                              const int* __restrict__ fl) {
  int isb = *fl;
  __shared__ float As[16][132];
  __shared__ float Ws[16][68];
  int tid = threadIdx.x;
  int tx = tid & 15, ty = tid >> 4;
  int m0 = blockIdx.y * 128, n0 = blockIdx.x * 64;
  float acc[8][4] = {};
  for (int k0 = 0; k0 < K; k0 += 16) {
#pragma unroll
    for (int i = 0; i < 2; ++i) {
      int idx4 = tid + i * 256;           // 512 float4 units = 128x16 tile
      int mm = idx4 >> 2, kc = (idx4 & 3) * 4;
      float4 v = *(const float4*)(A + (long)(m0 + mm) * K + k0 + kc);
      As[kc][mm] = v.x; As[kc + 1][mm] = v.y; As[kc + 2][mm] = v.z; As[kc + 3][mm] = v.w;
    }
#pragma unroll
    for (int i = 0; i < 4; ++i) {
      int idx = tid + i * 256;            // 1024 elements = 64x16 tile
      int nn = idx >> 4, kk = idx & 15;
      int gn = n0 + nn, gk = k0 + kk;
      Ws[kk][nn] = (gn < N && gk < Kw) ? ldw(W, woff + (long)gn * Kw + gk, isb) : 0.0f;
    }
    __syncthreads();
#pragma unroll
    for (int kk = 0; kk < 16; ++kk) {
      float4 a0 = *(const float4*)&As[kk][ty * 8];
      float4 a1 = *(const float4*)&As[kk][ty * 8 + 4];
      float4 w4 = *(const float4*)&Ws[kk][tx * 4];
      float av[8] = {a0.x, a0.y, a0.z, a0.w, a1.x, a1.y, a1.z, a1.w};
      float wv[4] = {w4.x, w4.y, w4.z, w4.w};
#pragma unroll
      for (int i = 0; i < 8; ++i)
#pragma unroll
        for (int j = 0; j < 4; ++j) acc[i][j] += av[i] * wv[j];
    }
    __syncthreads();
  }
#pragma unroll
  for (int i = 0; i < 8; ++i) {
    int gm = m0 + ty * 8 + i;
#pragma unroll
    for (int j = 0; j < 4; ++j) {
      int gn = n0 + tx * 4 + j;
      if (gn >= N) continue;
      float v = acc[i][j] + ldw(bias, boff + gn, isb);
      if (HASRES) v += res[(long)gm * N + gn];
      if (ACT == 1) v = gelu_exact(v);
      C[(long)gm * N + gn] = v;
    }
  }
}

// ---------------- fused attention (flash, Br=16, Bc=64), heads=4, HD=48, N=1024/pair --------
__global__ __launch_bounds__(256) void k_attn(const float* __restrict__ qkv, float* __restrict__ y) {
  __shared__ float Qs[16][52];
  __shared__ float Ks[64][52];
  __shared__ float Vs[64][52];
  __shared__ float S[16][68];
  __shared__ float mS[16], lS[16], aS[16];
  int tid = threadIdx.x;
  int h = blockIdx.y, b = blockIdx.z;
  int q0 = blockIdx.x * 16;
  const float* base = qkv + (long)b * 1024 * 576;
  const float SC = 0.14433756729740643f; // 1/sqrt(48)
  for (int i = tid; i < 192; i += 256) {  // 16 rows x 12 chunks
    int r = i / 12, ch = i % 12;
    float4 v = *(const float4*)(base + (long)(q0 + r) * 576 + h * 48 + ch * 4);
    v.x *= SC; v.y *= SC; v.z *= SC; v.w *= SC;
    *(float4*)&Qs[r][ch * 4] = v;
  }
  if (tid < 16) { mS[tid] = -1e30f; lS[tid] = 0.0f; }
  int pr = tid / 12, pch = tid % 12;  // PV ownership (tid < 192)
  float4 o = {0.0f, 0.0f, 0.0f, 0.0f};
  __syncthreads();
  for (int kc = 0; kc < 16; ++kc) {
    int k0 = kc * 64;
    for (int i = tid; i < 768; i += 256) {  // 64 rows x 12 chunks
      int r = i / 12, ch = i % 12;
      *(float4*)&Ks[r][ch * 4] =
          *(const float4*)(base + (long)(k0 + r) * 576 + 192 + h * 48 + ch * 4);
      *(float4*)&Vs[r][ch * 4] =
          *(const float4*)(base + (long)(k0 + r) * 576 + 384 + h * 48 + ch * 4);
    }
    __syncthreads();
    {
      int c = tid & 63, rb = tid >> 6;  // rows rb, rb+4, rb+8, rb+12
      float s0 = 0, s1 = 0, s2 = 0, s3 = 0;
#pragma unroll
      for (int ch = 0; ch < 12; ++ch) {
        float4 k4 = *(const float4*)&Ks[c][ch * 4];
        float4 q;
        q = *(const float4*)&Qs[rb][ch * 4];
        s0 += q.x * k4.x + q.y * k4.y + q.z * k4.z + q.w * k4.w;
        q = *(const float4*)&Qs[rb + 4][ch * 4];
        s1 += q.x * k4.x + q.y * k4.y + q.z * k4.z + q.w * k4.w;
        q = *(const float4*)&Qs[rb + 8][ch * 4];
        s2 += q.x * k4.x + q.y * k4.y + q.z * k4.z + q.w * k4.w;
        q = *(const float4*)&Qs[rb + 12][ch * 4];
        s3 += q.x * k4.x + q.y * k4.y + q.z * k4.z + q.w * k4.w;
      }
      S[rb][c] = s0; S[rb + 4][c] = s1; S[rb + 8][c] = s2; S[rb + 12][c] = s3;
    }
    __syncthreads();
    {
      int g = tid >> 4, l = tid & 15;
      float v0 = S[g][l], v1 = S[g][l + 16], v2 = S[g][l + 32], v3 = S[g][l + 48];
      float mx = fmaxf(fmaxf(v0, v1), fmaxf(v2, v3));
      for (int o2 = 8; o2; o2 >>= 1) mx = fmaxf(mx, __shfl_xor(mx, o2, 16));
      float mOld = mS[g];
      mx = fmaxf(mx, mOld);
      float p0 = __expf(v0 - mx), p1 = __expf(v1 - mx), p2 = __expf(v2 - mx), p3 = __expf(v3 - mx);
      S[g][l] = p0; S[g][l + 16] = p1; S[g][l + 32] = p2; S[g][l + 48] = p3;
      float sum = p0 + p1 + p2 + p3;
      for (int o2 = 8; o2; o2 >>= 1) sum += __shfl_xor(sum, o2, 16);
      if (l == 0) {
        float alpha = __expf(mOld - mx);
        aS[g] = alpha;
        lS[g] = lS[g] * alpha + sum;
        mS[g] = mx;
      }
    }
    __syncthreads();
    if (tid < 192) {
      float a = aS[pr];
      o.x *= a; o.y *= a; o.z *= a; o.w *= a;
#pragma unroll
      for (int c4 = 0; c4 < 16; ++c4) {
        float4 s4 = *(const float4*)&S[pr][c4 * 4];
        float4 v;
        v = *(const float4*)&Vs[c4 * 4 + 0][pch * 4];
        o.x += s4.x * v.x; o.y += s4.x * v.y; o.z += s4.x * v.z; o.w += s4.x * v.w;
        v = *(const float4*)&Vs[c4 * 4 + 1][pch * 4];
        o.x += s4.y * v.x; o.y += s4.y * v.y; o.z += s4.y * v.z; o.w += s4.y * v.w;
        v = *(const float4*)&Vs[c4 * 4 + 2][pch * 4];
        o.x += s4.z * v.x; o.y += s4.z * v.y; o.z += s4.z * v.z; o.w += s4.z * v.w;
        v = *(const float4*)&Vs[c4 * 4 + 3][pch * 4];
        o.x += s4.w * v.x; o.y += s4.w * v.y; o.z += s4.w * v.z; o.w += s4.w * v.w;
      }
    }
    __syncthreads();
  }
  if (tid < 192) {
    float inv = 1.0f / lS[pr];
    o.x *= inv; o.y *= inv; o.z *= inv; o.w *= inv;
    *(float4*)(y + (long)b * 1024 * 192 + (long)(q0 + pr) * 192 + h * 48 + pch * 4) = o;
  }
}

// ---------------- EMA: x[pair1] = 0.8*x[pair1] + 0.2*x[pair0] ----------------
__global__ void k_ema(float* __restrict__ x) {
  int i = blockIdx.x * blockDim.x + threadIdx.x;
  if (i < 196608) x[196608 + i] = 0.8f * x[196608 + i] + 0.2f * x[i];
}

// ---------------- fv (2048x2) -> flow [b][2][1024] ----------------
__global__ void k_fv2flow(const float* __restrict__ fv, float* __restrict__ cur) {
  int i = blockIdx.x * blockDim.x + threadIdx.x;
  if (i < 4096) {
    int b = i >> 11, r = i & 2047;
    int c = r >> 10, p = r & 1023;
    cur[i] = fv[(long)(b * 1024 + p) * 2 + c];
  }
}

// ---------------- warp (bilinear, border clamp); img for pair b is imgbase[(b+1)] --------
__global__ void k_warp(const float* __restrict__ imgbase, const float* __restrict__ flow,
                       float* __restrict__ out, int C, int H, int W) {
  int HW = H * W;
  int per = C * HW;
  int i = blockIdx.x * blockDim.x + threadIdx.x;
  if (i >= 2 * per) return;
  int b = i / per;
  int rem = i - b * per;
  int c = rem / HW;
  int p = rem - c * HW;
  int h = p / W, w = p - h * W;
  const float* img = imgbase + (long)(b + 1) * per;
  const float* fl = flow + (long)b * 2 * HW;
  float x = fminf(fmaxf((float)w + fl[p], 0.0f), (float)(W - 1));
  float yy = fminf(fmaxf((float)h + fl[HW + p], 0.0f), (float)(H - 1));
  int x0 = (int)floorf(x), y0 = (int)floorf(yy);
  int x1 = min(x0 + 1, W - 1), y1 = min(y0 + 1, H - 1);
  float wx = x - (float)x0, wy = yy - (float)y0;
  const float* ic = img + (long)c * HW;
  float v00 = ic[y0 * W + x0], v01 = ic[y0 * W + x1];
  float v10 = ic[y1 * W + x0], v11 = ic[y1 * W + x1];
  out[i] = v00 * (1 - wx) * (1 - wy) + v01 * wx * (1 - wy) + v10 * (1 - wx) * wy + v11 * wx * wy;
}

// ---------------- 3x3 conv phase 1: partial sums over an input-channel split -----------
// 16x16 spatial tile, OCG output channels/thread, 8-channel LDS batches, transposed
// fp32 weights [ICT][OC][9] (contiguous per (ic, oc-group) -> uniform s_load bursts).
// grid: (spatialTiles, OC/OCG, 2*NS); partial chunk s lives at
//   (s < na ? pa + s*Sa : pb + (s-na)*Sa), chunk layout [b][oc][H*W], Sa = 2*OC*H*W.
template <int OCG>
__global__ __launch_bounds__(256) void k_conv_part(
    const float* __restrict__ s0, int c0, long s0bs,
    const float* __restrict__ s1, int c1, long s1bs,
    const float* __restrict__ s2, int c2, long s2bs,
    const float* __restrict__ wT, int OC,
    float* __restrict__ pa, long Sa, int na, float* __restrict__ pb,
    int H, int W, int NS) {
  __shared__ float T[8][18][20];
  int tid = threadIdx.x;
  int nTx = W >> 4;
  int ty0 = (blockIdx.x / nTx) << 4, tx0 = (blockIdx.x % nTx) << 4;
  int oc0 = blockIdx.y * OCG;
  int z = blockIdx.z;
  int b = z / NS, s = z - b * NS;
  int ICT = c0 + c1 + c2;
  int csz = (ICT + NS - 1) / NS;
  int g0 = s * csz, g1 = min(ICT, g0 + csz);
  float acc[OCG] = {};
  int ly = tid >> 4, lx = tid & 15;
  const float* sp0 = s0 + (long)b * s0bs;
  const float* sp1 = s1 ? s1 + (long)b * s1bs : nullptr;
  const float* sp2 = s2 ? s2 + (long)b * s2bs : nullptr;
  for (int gc = g0; gc < g1; gc += 8) {
    int nb = min(8, g1 - gc);
    for (int i = tid; i < nb * 324; i += 256) {
      int bch = i / 324, w2 = i - bch * 324;
      int rr = w2 / 18, cc = w2 - rr * 18;
      int yy = ty0 - 1 + rr, xx = tx0 - 1 + cc;
      int gch = gc + bch;
      const float* sp; int lc;
      if (gch < c0) { sp = sp0; lc = gch; }
      else if (gch < c0 + c1) { sp = sp1; lc = gch - c0; }
      else { sp = sp2; lc = gch - c0 - c1; }
      T[bch][rr][cc] = (yy >= 0 && yy < H && xx >= 0 && xx < W)
                           ? sp[(long)lc * H * W + yy * W + xx] : 0.0f;
    }
    __syncthreads();
    for (int j = 0; j < nb; ++j) {
      float t00 = T[j][ly][lx],     t01 = T[j][ly][lx + 1],     t02 = T[j][ly][lx + 2];
      float t10 = T[j][ly + 1][lx], t11 = T[j][ly + 1][lx + 1], t12 = T[j][ly + 1][lx + 2];
      float t20 = T[j][ly + 2][lx], t21 = T[j][ly + 2][lx + 1], t22 = T[j][ly + 2][lx + 2];
      const float* wp = wT + ((long)(gc + j) * OC + oc0) * 9;
#pragma unroll
      for (int o = 0; o < OCG; ++o) {
        const float* w9 = wp + o * 9;
        acc[o] += t00 * w9[0] + t01 * w9[1] + t02 * w9[2]
                + t10 * w9[3] + t11 * w9[4] + t12 * w9[5]
                + t20 * w9[6] + t21 * w9[7] + t22 * w9[8];
      }
    }
    __syncthreads();
  }
  float* base = (s < na) ? pa + (long)s * Sa : pb + (long)(s - na) * Sa;
  long p = (long)(ty0 + ly) * W + (tx0 + lx);
#pragma unroll
  for (int o = 0; o < OCG; ++o)
    base[((long)b * OC + (oc0 + o)) * (long)(H * W) + p] = acc[o];
}

// phase 2: out = [gelu](bias + sum of partial chunks) [+ res]; i spans 2*OC*HW
__global__ void k_conv_fin(const float* __restrict__ pa, long Sa, int na,
                           const float* __restrict__ pb, int nb2,
                           const float* __restrict__ bias, const float* __restrict__ res,
                           float* __restrict__ out, int OC, int HW, int act, int n) {
  int i = blockIdx.x * blockDim.x + threadIdx.x;
  if (i >= n) return;
  int oc = (i / HW) % OC;
  float v = bias[oc];
  for (int s = 0; s < na; ++s) v += pa[(long)s * Sa + i];
  for (int s = 0; s < nb2; ++s) v += pb[(long)s * Sa + i];
  if (act) v = gelu_exact(v);
  if (res) v += res[i];
  out[i] = v;
}

// ---------------- 2x align-corners bilinear upsample (2x2x32x32 -> 2x2x64x64) -------------
__global__ void k_upsample(const float* __restrict__ in, float* __restrict__ out) {
  int i = blockIdx.x * blockDim.x + threadIdx.x;
  if (i >= 2 * 2 * 64 * 64) return;
  int p = i & 4095;
  int bc = i >> 12;
  int oy = p >> 6, ox = p & 63;
  float sx = ox * (31.0f / 63.0f), sy = oy * (31.0f / 63.0f);
  int x0 = (int)sx, y0 = (int)sy;
  int x1 = min(x0 + 1, 31), y1 = min(y0 + 1, 31);
  float wx = sx - x0, wy = sy - y0;
  const float* ic = in + (long)bc * 1024;
  out[i] = ic[y0 * 32 + x0] * (1 - wx) * (1 - wy) + ic[y0 * 32 + x1] * wx * (1 - wy)
         + ic[y1 * 32 + x0] * (1 - wx) * wy      + ic[y1 * 32 + x1] * wx * wy;
}

// ---------------- final write (fp32 -> bf16|fp32 per detected dtype) ----------------
__global__ void k_out(const float* __restrict__ cur2, void* __restrict__ out,
                      const int* __restrict__ fl) {
  int isb = *fl;
  int i = blockIdx.x * blockDim.x + threadIdx.x;
  if (i < 16384) {
    if (isb) ((bf16*)out)[i] = f2bf(cur2[i]);
    else ((float*)out)[i] = cur2[i];
  }
}

extern "C" void kernel_launch(void* const* d_in, const int* in_sizes, int n_in,
                              void* d_out, int out_size, void* d_ws, size_t ws_size,
                              hipStream_t stream) {
  const void* feats_l1 = d_in[0];
  const void* feats_l2 = d_in[1];
  const void* tok_w = d_in[3];
  const void* tok_b = d_in[4];
  const void* lcm_ln1_w = d_in[5];
  const void* lcm_ln1_b = d_in[6];
  const void* lcm_in_w  = d_in[7];
  const void* lcm_in_b  = d_in[8];
  const void* lcm_out_w = d_in[9];
  const void* lcm_out_b = d_in[10];
  const void* lcm_ln2_w = d_in[11];
  const void* lcm_ln2_b = d_in[12];
  const void* lcm_mlp_w1 = d_in[13];
  const void* lcm_mlp_b1 = d_in[14];
  const void* lcm_mlp_w2 = d_in[15];
  const void* lcm_mlp_b2 = d_in[16];
  const void* gtr_ln1_w = d_in[17];
  const void* gtr_ln1_b = d_in[18];
  const void* gtr_in_w  = d_in[19];
  const void* gtr_in_b  = d_in[20];
  const void* gtr_out_w = d_in[21];
  const void* gtr_out_b = d_in[22];
  const void* gtr_ln2_w = d_in[23];
  const void* gtr_ln2_b = d_in[24];
  const void* gtr_mlp_w1 = d_in[25];
  const void* gtr_mlp_b1 = d_in[26];
  const void* gtr_mlp_w2 = d_in[27];
  const void* gtr_mlp_b2 = d_in[28];
  const void* head_w1 = d_in[29];
  const void* head_b1 = d_in[30];
  const void* head_w2 = d_in[31];
  const void* head_b2 = d_in[32];
  const void* ref1_w1 = d_in[33];
  const void* ref1_b1 = d_in[34];
  const void* ref1_w2 = d_in[35];
  const void* ref1_b2 = d_in[36];
  const void* ref0_w1 = d_in[37];
  const void* ref0_b1 = d_in[38];
  const void* ref0_w2 = d_in[39];
  const void* ref0_b2 = d_in[40];
  (void)ws_size; (void)n_in; (void)in_sizes; (void)out_size;

  // ---- workspace layout (fp32; ~17.3 MB, same footprint as round 3) ----
  int* flag = (int*)d_ws;
  float* wsf = (float*)d_ws;
  float* F2  = wsf + 16;              // 393216
  float* F1  = F2 + 393216;           // 786432
  float* x   = F1 + 786432;           // 393216  (x..yb = 1179648 contiguous, reused for partials)
  float* ta  = x + 393216;            // 393216
  float* yb  = ta + 393216;           // 393216
  float* big = yb + 393216;           // 1572864: corrT | qkvb | hid | decoder scratch
  float* fv  = big + 1572864;         // 4096
  float* cur = fv + 4096;             // 4096   [2][2][1024]
  float* cur2 = cur + 4096;           // 16384  [2][2][4096]
  float* cwT1a = cur2 + 16384;        // 297216 : ref1_w1 fp32 transposed [258][128][9]
  float* cb1a  = cwT1a + 297216;      // 128
  float* cwT1b = cb1a + 128;          // 2304   : ref1_w2 [128][2][9]
  float* cb1b  = cwT1b + 2304;        // 16 (2 used)
  float* cwT0a = cb1b + 16;           // 74880  : ref0_w1 [130][64][9]
  float* cb0a  = cwT0a + 74880;       // 64
  float* cwT0b = cb0a + 64;           // 1152   : ref0_w2 [64][2][9]
  float* cb0b  = cwT0b + 1152;        // 16 (2 used)
  float* corrT = big;                 // 2048 x 64 (zero-padded K)
  float* qkvb = big;                  // 2048 x 576
  float* hid  = big;                  // 2048 x 768
  float* wp1  = big;                  // [2][128][1024]
  float* mid1 = big + 262144;         // [2][128][1024]
  float* wp0  = big;                  // [2][64][4096]
  float* mid0 = big + 524288;         // [2][64][4096]
  float* bigtail = big + 1048576;     // 524288 free during decoder (3rd l0-conv1 chunk)
  float* p1b  = big + 524288;         // l1-conv2 partials (16 x 4096) during l1 phase

  k_detect<<<1, 256, 0, stream>>>((const unsigned short*)feats_l1, flag);
  k_cvt<<<1536, 256, 0, stream>>>(feats_l2, F2, 393216, flag);
  k_cvt<<<3072, 256, 0, stream>>>(feats_l1, F1, 786432, flag);
  // conv weights -> fp32 transposed [ic][oc][9]; biases -> fp32
  k_cvt_trans<<<1161, 256, 0, stream>>>(ref1_w1, cwT1a, 128, 258, 297216, flag);
  k_cvt<<<1, 256, 0, stream>>>(ref1_b1, cb1a, 128, flag);
  k_cvt_trans<<<9, 256, 0, stream>>>(ref1_w2, cwT1b, 2, 128, 2304, flag);
  k_cvt<<<1, 256, 0, stream>>>(ref1_b2, cb1b, 2, flag);
  k_cvt_trans<<<293, 256, 0, stream>>>(ref0_w1, cwT0a, 64, 130, 74880, flag);
  k_cvt<<<1, 256, 0, stream>>>(ref0_b1, cb0a, 64, flag);
  k_cvt_trans<<<5, 256, 0, stream>>>(ref0_w2, cwT0b, 2, 64, 1152, flag);
  k_cvt<<<1, 256, 0, stream>>>(ref0_b2, cb0b, 2, flag);

  // ---- tokens (level 1 only): corr (K padded to 64) then tokenizer GEMM ----
  k_corr<<<dim3(1024, 2), 64, 0, stream>>>(F2, corrT);
  k_gemm<0, false><<<dim3(3, 16), 256, 0, stream>>>(corrT, tok_w, 9408, tok_b, 192, nullptr,
                                                    x, 2048, 192, 64, 49, flag);

  auto run_block = [&](const void* ln1w, long o1, const void* ln1b, long o2,
                       const void* inw, long o3, const void* inb, long o4,
                       const void* ow, long o5, const void* ob, long o6,
                       const void* ln2w, long o7, const void* ln2b, long o8,
                       const void* w1, long o9, const void* b1, long o10,
                       const void* w2, long o11, const void* b2, long o12) {
    k_ln<<<2048, 64, 0, stream>>>(x, ta, ln1w, o1, ln1b, o2, flag);
    k_gemm<0, false><<<dim3(9, 16), 256, 0, stream>>>(ta, inw, o3, inb, o4, nullptr, qkvb,
                                                      2048, 576, 192, 192, flag);
    k_attn<<<dim3(64, 4, 2), 256, 0, stream>>>(qkvb, yb);
    k_gemm<0, true><<<dim3(3, 16), 256, 0, stream>>>(yb, ow, o5, ob, o6, x, x,
                                                     2048, 192, 192, 192, flag);
    k_ln<<<2048, 64, 0, stream>>>(x, ta, ln2w, o7, ln2b, o8, flag);
    k_gemm<1, false><<<dim3(12, 16), 256, 0, stream>>>(ta, w1, o9, b1, o10, nullptr, hid,
                                                       2048, 768, 192, 192, flag);
    k_gemm<0, true><<<dim3(3, 16), 256, 0, stream>>>(hid, w2, o11, b2, o12, x, x,
                                                     2048, 192, 768, 768, flag);
  };

  // ---- LCM: 6 blocks, both pairs batched (rows 0..1023 = pair0, 1024..2047 = pair1) ----
  for (int i = 0; i < 6; ++i) {
    run_block(lcm_ln1_w, (long)i * 192, lcm_ln1_b, (long)i * 192,
              lcm_in_w, (long)i * 110592, lcm_in_b, (long)i * 576,
              lcm_out_w, (long)i * 36864, lcm_out_b, (long)i * 192,
              lcm_ln2_w, (long)i * 192, lcm_ln2_b, (long)i * 192,
              lcm_mlp_w1, (long)i * 147456, lcm_mlp_b1, (long)i * 768,
              lcm_mlp_w2, (long)i * 147456, lcm_mlp_b2, (long)i * 192);
  }
  k_ema<<<768, 256, 0, stream>>>(x);

  // ---- GTR: 2 blocks ----
  for (int i = 0; i < 2; ++i) {
    run_block(gtr_ln1_w, (long)i * 192, gtr_ln1_b, (long)i * 192,
              gtr_in_w, (long)i * 110592, gtr_in_b, (long)i * 576,
              gtr_out_w, (long)i * 36864, gtr_out_b, (long)i * 192,
              gtr_ln2_w, (long)i * 192, gtr_ln2_b, (long)i * 192,
              gtr_mlp_w1, (long)i * 147456, gtr_mlp_b1, (long)i * 768,
              gtr_mlp_w2, (long)i * 147456, gtr_mlp_b2, (long)i * 192);
  }

  // ---- head -> coarse flow ----
  k_gemm<1, false><<<dim3(3, 16), 256, 0, stream>>>(x, head_w1, 0, head_b1, 0, nullptr, ta,
                                                    2048, 192, 192, 192, flag);
  k_gemm<0, false><<<dim3(1, 16), 256, 0, stream>>>(ta, head_w2, 0, head_b2, 0, nullptr, fv,
                                                    2048, 2, 192, 192, flag);
  k_fv2flow<<<16, 256, 0, stream>>>(fv, cur);

  // ---- decoder level 1 (32x32, feats_l2); IC=258 split NS=4, chunks in x.. ----
  for (int it = 0; it < 4; ++it) {
    k_warp<<<1024, 256, 0, stream>>>(F2, cur, wp1, 128, 32, 32);
    k_conv_part<8><<<dim3(4, 16, 8), 256, 0, stream>>>(
        F2, 128, 131072, cur, 2, 2048, wp1, 128, 131072,
        cwT1a, 128, x, 262144, 4, nullptr, 32, 32, 4);
    k_conv_fin<<<1024, 256, 0, stream>>>(x, 262144, 4, nullptr, 0, cb1a, nullptr,
                                         mid1, 128, 1024, 1, 262144);
    k_conv_part<2><<<dim3(4, 1, 32), 256, 0, stream>>>(
        mid1, 128, 131072, nullptr, 0, 0, nullptr, 0, 0,
        cwT1b, 2, p1b, 4096, 16, nullptr, 32, 32, 16);
    k_conv_fin<<<32, 256, 0, stream>>>(p1b, 4096, 16, nullptr, 0, cb1b, cur,
                                       cur, 2, 1024, 0, 8192);
  }
  k_upsample<<<64, 256, 0, stream>>>(cur, cur2);

  // ---- decoder level 0 (64x64, feats_l1); IC=130 split NS=3 (2 chunks in x.., 1 in big) ----
  for (int it = 0; it < 4; ++it) {
    k_warp<<<2048, 256, 0, stream>>>(F1, cur2, wp0, 64, 64, 64);
    k_conv_part<8><<<dim3(16, 8, 6), 256, 0, stream>>>(
        F1, 64, 262144, cur2, 2, 8192, wp0, 64, 262144,
        cwT0a, 64, x, 524288, 2, bigtail, 64, 64, 3);
    k_conv_fin<<<2048, 256, 0, stream>>>(x, 524288, 2, bigtail, 1, cb0a, nullptr,
                                         mid0, 64, 4096, 1, 524288);
    k_conv_part<2><<<dim3(16, 1, 16), 256, 0, stream>>>(
        mid0, 64, 262144, nullptr, 0, 0, nullptr, 0, 0,
        cwT0b, 2, x, 16384, 8, nullptr, 64, 64, 8);
    k_conv_fin<<<128, 256, 0, stream>>>(x, 16384, 8, nullptr, 0, cb0b, cur2,
                                        cur2, 2, 4096, 0, 32768);
  }

  k_out<<<64, 256, 0, stream>>>(cur2, d_out, flag);
}

// Round 5
// 1836.687 us; speedup vs baseline: 3.9243x; 1.7286x over previous
//
#include <hip/hip_runtime.h>
#include <hip/hip_bf16.h>

typedef __hip_bfloat16 bf16;
typedef short bf16x8 __attribute__((ext_vector_type(8)));
typedef float f32x4 __attribute__((ext_vector_type(4)));

#define DEV __device__ __forceinline__

DEV float bf2f(bf16 v) { return __bfloat162float(v); }
DEV bf16 f2bf(float v) { return __float2bfloat16(v); }
DEV unsigned short bfr(float f) {
  bf16 h = __float2bfloat16(f);
  return *reinterpret_cast<unsigned short*>(&h);
}
DEV float gelu_exact(float x) { return 0.5f * x * (1.0f + erff(x * 0.70710678118654752f)); }

// load a "reference float32" parameter that may physically be bf16 or fp32
DEV float ldw(const void* p, long i, int isb) {
  return isb ? __bfloat162float(((const bf16*)p)[i]) : ((const float*)p)[i];
}

// ---------------- dtype detection + flag constants ----------------
__global__ void k_detect(const unsigned short* __restrict__ u, int* __restrict__ flag) {
  __shared__ int bad;
  if (threadIdx.x == 0) bad = 0;
  __syncthreads();
  for (int i = threadIdx.x; i < 8192; i += 256) {
    int expo = (u[i] >> 7) & 0xFF;
    if (expo >= 138) atomicOr(&bad, 1);
  }
  __syncthreads();
  if (threadIdx.x == 0) *flag = bad ? 0 : 1;
}
__global__ void k_setone(int* p) { *p = 1; }

// ---------------- convert (bf16|fp32) -> fp32 ----------------
__global__ void k_cvt(const void* __restrict__ s, float* __restrict__ d, int n,
                      const int* __restrict__ fl) {
  int isb = *fl;
  int i = blockIdx.x * blockDim.x + threadIdx.x;
  if (i < n) d[i] = ldw(s, i, isb);
}

// convert + transpose conv weights [OC][ICT][9] -> fp32 [ICT][OC][9]
__global__ void k_cvt_trans(const void* __restrict__ s, float* __restrict__ d,
                            int OC, int ICT, int n, const int* __restrict__ fl) {
  int isb = *fl;
  int i = blockIdx.x * blockDim.x + threadIdx.x;
  if (i >= n) return;
  int oc = i / (ICT * 9);
  int r = i - oc * ICT * 9;
  int ic = r / 9, k = r - ic * 9;
  d[((long)ic * OC + oc) * 9 + k] = ldw(s, i, isb);
}

// tokenizer weight [192][49] (at element offset 9408) -> bf16 [192][64] zero-padded
__global__ void k_padtokw(const void* __restrict__ tw, bf16* __restrict__ dst,
                          const int* __restrict__ fl) {
  int isb = *fl;
  int i = blockIdx.x * blockDim.x + threadIdx.x;
  if (i >= 12288) return;
  int n = i >> 6, k = i & 63;
  float v = (k < 49) ? ldw(tw, 9408 + (long)n * 49 + k, isb) : 0.0f;
  dst[i] = f2bf(v);
}

// ---------------- local correlation (level 1), output stride 64 (zero-padded) -------------
__global__ void k_corr(const float* __restrict__ F2, float* __restrict__ corrT) {
  __shared__ float f1v[128];
  int p = blockIdx.x;          // pixel 0..1023
  int b = blockIdx.y;          // pair 0..1
  int t = threadIdx.x;         // 64 threads
  const float* f1 = F2 + (long)b * 131072;
  const float* f2 = F2 + (long)(b + 1) * 131072;
  f1v[t]      = f1[t * 1024 + p];
  f1v[t + 64] = f1[(t + 64) * 1024 + p];
  __syncthreads();
  long rowo = ((long)b * 1024 + p) * 64;
  if (t < 49) {
    int dy = t / 7 - 3, dx = t % 7 - 3;
    int h = p >> 5, w = p & 31;
    int p2 = (((h - dy) & 31) << 5) | ((w - dx) & 31);
    float s = 0.0f;
    for (int c = 0; c < 128; ++c) s += f1v[c] * f2[c * 1024 + p2];
    corrT[rowo + t] = s * 0.08838834764831845f; // 1/sqrt(128)
  } else {
    corrT[rowo + t] = 0.0f;
  }
}

// ---------------- LayerNorm (D=192), one wave per row, direct weights ----------------
__global__ void k_ln(const float* __restrict__ src, float* __restrict__ dst,
                     const void* __restrict__ w, long woff,
                     const void* __restrict__ b, long boff,
                     const int* __restrict__ fl) {
  int isb = *fl;
  int row = blockIdx.x;
  int t = threadIdx.x; // 64
  const float* s = src + (long)row * 192;
  float e0 = s[t], e1 = s[t + 64], e2 = s[t + 128];
  float sum = e0 + e1 + e2;
  for (int o = 32; o; o >>= 1) sum += __shfl_xor(sum, o);
  float mean = sum * (1.0f / 192.0f);
  float d0 = e0 - mean, d1 = e1 - mean, d2 = e2 - mean;
  float vs = d0 * d0 + d1 * d1 + d2 * d2;
  for (int o = 32; o; o >>= 1) vs += __shfl_xor(vs, o);
  float rstd = rsqrtf(vs * (1.0f / 192.0f) + 1e-5f);
  float* o_ = dst + (long)row * 192;
  o_[t]       = d0 * rstd * ldw(w, woff + t, isb)       + ldw(b, boff + t, isb);
  o_[t + 64]  = d1 * rstd * ldw(w, woff + t + 64, isb)  + ldw(b, boff + t + 64, isb);
  o_[t + 128] = d2 * rstd * ldw(w, woff + t + 128, isb) + ldw(b, boff + t + 128, isb);
}

// ---------------- MFMA bf16 GEMM: C(MxN) = A(MxK) @ W(NxK)^T + bias (+res) (+gelu) --------
// BM=BN=64, 256 threads = 4 waves; wave w owns rows [w*16, w*16+16) x 64 cols.
// K-chunks of 32 staged via LDS (A fp32 -> bf16 RNE; W bf16 direct / fp32 packed).
// Verified gfx950 16x16x32 fragment layouts: A[m=lane&15][k=quad*8+j],
// B from W[n][k] with n=lane&15, k=quad*8+j; D col=lane&15, row=quad*4+reg.
// Requires: M%64==0, N%64==0, K%32==0.
template <int ACT, bool HASRES>
__global__ __launch_bounds__(256) void k_gemm_mfma(
    const float* __restrict__ A, const void* __restrict__ W, long woff,
    const void* __restrict__ bias, long boff, const int* __restrict__ flb,
    const float* __restrict__ res, float* __restrict__ C,
    int M, int N, int K, const int* __restrict__ fl) {
  int isb = *fl;
  __shared__ unsigned short Asm[64][40];  // row stride 80 B (16B-aligned chunks)
  __shared__ unsigned short Wsm[64][40];
  int tid = threadIdx.x;
  int wv = tid >> 6, ln = tid & 63;
  int quad = ln >> 4, l16 = ln & 15;
  int m0 = blockIdx.y * 64, n0 = blockIdx.x * 64;
  int srow = tid >> 2;          // staging row 0..63
  int skc = (tid & 3) * 8;      // staging k-offset 0,8,16,24
  f32x4 acc[4] = {};
  for (int k0 = 0; k0 < K; k0 += 32) {
    // stage A (fp32 -> bf16)
    {
      const float* ap = A + (long)(m0 + srow) * K + k0 + skc;
      float4 a0 = *(const float4*)ap;
      float4 a1 = *(const float4*)(ap + 4);
      union { unsigned short u[8]; float4 v; } pk;
      pk.u[0] = bfr(a0.x); pk.u[1] = bfr(a0.y); pk.u[2] = bfr(a0.z); pk.u[3] = bfr(a0.w);
      pk.u[4] = bfr(a1.x); pk.u[5] = bfr(a1.y); pk.u[6] = bfr(a1.z); pk.u[7] = bfr(a1.w);
      *(float4*)&Asm[srow][skc] = pk.v;
    }
    // stage W
    {
      long eo = woff + (long)(n0 + srow) * K + k0 + skc;
      if (isb) {
        *(float4*)&Wsm[srow][skc] = *(const float4*)((const unsigned short*)W + eo);
      } else {
        const float* wp = (const float*)W + eo;
        float4 w0 = *(const float4*)wp;
        float4 w1 = *(const float4*)(wp + 4);
        union { unsigned short u[8]; float4 v; } pk;
        pk.u[0] = bfr(w0.x); pk.u[1] = bfr(w0.y); pk.u[2] = bfr(w0.z); pk.u[3] = bfr(w0.w);
        pk.u[4] = bfr(w1.x); pk.u[5] = bfr(w1.y); pk.u[6] = bfr(w1.z); pk.u[7] = bfr(w1.w);
        *(float4*)&Wsm[srow][skc] = pk.v;
      }
    }
    __syncthreads();
    bf16x8 af = *(const bf16x8*)&Asm[wv * 16 + l16][quad * 8];
#pragma unroll
    for (int nt = 0; nt < 4; ++nt) {
      bf16x8 wf = *(const bf16x8*)&Wsm[nt * 16 + l16][quad * 8];
      acc[nt] = __builtin_amdgcn_mfma_f32_16x16x32_bf16(af, wf, acc[nt], 0, 0, 0);
    }
    __syncthreads();
  }
  int isbb = *flb;
#pragma unroll
  for (int nt = 0; nt < 4; ++nt) {
    int n = n0 + nt * 16 + l16;
    float bv = ldw(bias, boff + n, isbb);
#pragma unroll
    for (int r = 0; r < 4; ++r) {
      int m = m0 + wv * 16 + quad * 4 + r;
      float v = acc[nt][r] + bv;
      if (HASRES) v += res[(long)m * N + n];
      if (ACT == 1) v = gelu_exact(v);
      C[(long)m * N + n] = v;
    }
  }
}

// ---------------- fp32 GEMM (kept for the N=2 head output only) ----------------
template <int ACT, bool HASRES>
__global__ __launch_bounds__(256) void k_gemm(const float* __restrict__ A,
                                              const void* __restrict__ W, long woff,
                                              const void* __restrict__ bias, long boff,
                                              const float* __restrict__ res,
                                              float* __restrict__ C, int M, int N, int K, int Kw,
                                              const int* __restrict__ fl) {
  int isb = *fl;
  __shared__ float As[16][132];
  __shared__ float Ws[16][68];
  int tid = threadIdx.x;
  int tx = tid & 15, ty = tid >> 4;
  int m0 = blockIdx.y * 128, n0 = blockIdx.x * 64;
  float acc[8][4] = {};
  for (int k0 = 0; k0 < K; k0 += 16) {
#pragma unroll
    for (int i = 0; i < 2; ++i) {
      int idx4 = tid + i * 256;
      int mm = idx4 >> 2, kc = (idx4 & 3) * 4;
      float4 v = *(const float4*)(A + (long)(m0 + mm) * K + k0 + kc);
      As[kc][mm] = v.x; As[kc + 1][mm] = v.y; As[kc + 2][mm] = v.z; As[kc + 3][mm] = v.w;
    }
#pragma unroll
    for (int i = 0; i < 4; ++i) {
      int idx = tid + i * 256;
      int nn = idx >> 4, kk = idx & 15;
      int gn = n0 + nn, gk = k0 + kk;
      Ws[kk][nn] = (gn < N && gk < Kw) ? ldw(W, woff + (long)gn * Kw + gk, isb) : 0.0f;
    }
    __syncthreads();
#pragma unroll
    for (int kk = 0; kk < 16; ++kk) {
      float4 a0 = *(const float4*)&As[kk][ty * 8];
      float4 a1 = *(const float4*)&As[kk][ty * 8 + 4];
      float4 w4 = *(const float4*)&Ws[kk][tx * 4];
      float av[8] = {a0.x, a0.y, a0.z, a0.w, a1.x, a1.y, a1.z, a1.w};
      float wv[4] = {w4.x, w4.y, w4.z, w4.w};
#pragma unroll
      for (int i = 0; i < 8; ++i)
#pragma unroll
        for (int j = 0; j < 4; ++j) acc[i][j] += av[i] * wv[j];
    }
    __syncthreads();
  }
#pragma unroll
  for (int i = 0; i < 8; ++i) {
    int gm = m0 + ty * 8 + i;
#pragma unroll
    for (int j = 0; j < 4; ++j) {
      int gn = n0 + tx * 4 + j;
      if (gn >= N) continue;
      float v = acc[i][j] + ldw(bias, boff + gn, isb);
      if (HASRES) v += res[(long)gm * N + gn];
      if (ACT == 1) v = gelu_exact(v);
      C[(long)gm * N + gn] = v;
    }
  }
}

// ---------------- fused attention (flash, Br=16, Bc=64), heads=4, HD=48, N=1024/pair --------
__global__ __launch_bounds__(256) void k_attn(const float* __restrict__ qkv, float* __restrict__ y) {
  __shared__ float Qs[16][52];
  __shared__ float Ks[64][52];
  __shared__ float Vs[64][52];
  __shared__ float S[16][68];
  __shared__ float mS[16], lS[16], aS[16];
  int tid = threadIdx.x;
  int h = blockIdx.y, b = blockIdx.z;
  int q0 = blockIdx.x * 16;
  const float* base = qkv + (long)b * 1024 * 576;
  const float SC = 0.14433756729740643f; // 1/sqrt(48)
  for (int i = tid; i < 192; i += 256) {
    int r = i / 12, ch = i % 12;
    float4 v = *(const float4*)(base + (long)(q0 + r) * 576 + h * 48 + ch * 4);
    v.x *= SC; v.y *= SC; v.z *= SC; v.w *= SC;
    *(float4*)&Qs[r][ch * 4] = v;
  }
  if (tid < 16) { mS[tid] = -1e30f; lS[tid] = 0.0f; }
  int pr = tid / 12, pch = tid % 12;
  float4 o = {0.0f, 0.0f, 0.0f, 0.0f};
  __syncthreads();
  for (int kc = 0; kc < 16; ++kc) {
    int k0 = kc * 64;
    for (int i = tid; i < 768; i += 256) {
      int r = i / 12, ch = i % 12;
      *(float4*)&Ks[r][ch * 4] =
          *(const float4*)(base + (long)(k0 + r) * 576 + 192 + h * 48 + ch * 4);
      *(float4*)&Vs[r][ch * 4] =
          *(const float4*)(base + (long)(k0 + r) * 576 + 384 + h * 48 + ch * 4);
    }
    __syncthreads();
    {
      int c = tid & 63, rb = tid >> 6;
      float s0 = 0, s1 = 0, s2 = 0, s3 = 0;
#pragma unroll
      for (int ch = 0; ch < 12; ++ch) {
        float4 k4 = *(const float4*)&Ks[c][ch * 4];
        float4 q;
        q = *(const float4*)&Qs[rb][ch * 4];
        s0 += q.x * k4.x + q.y * k4.y + q.z * k4.z + q.w * k4.w;
        q = *(const float4*)&Qs[rb + 4][ch * 4];
        s1 += q.x * k4.x + q.y * k4.y + q.z * k4.z + q.w * k4.w;
        q = *(const float4*)&Qs[rb + 8][ch * 4];
        s2 += q.x * k4.x + q.y * k4.y + q.z * k4.z + q.w * k4.w;
        q = *(const float4*)&Qs[rb + 12][ch * 4];
        s3 += q.x * k4.x + q.y * k4.y + q.z * k4.z + q.w * k4.w;
      }
      S[rb][c] = s0; S[rb + 4][c] = s1; S[rb + 8][c] = s2; S[rb + 12][c] = s3;
    }
    __syncthreads();
    {
      int g = tid >> 4, l = tid & 15;
      float v0 = S[g][l], v1 = S[g][l + 16], v2 = S[g][l + 32], v3 = S[g][l + 48];
      float mx = fmaxf(fmaxf(v0, v1), fmaxf(v2, v3));
      for (int o2 = 8; o2; o2 >>= 1) mx = fmaxf(mx, __shfl_xor(mx, o2, 16));
      float mOld = mS[g];
      mx = fmaxf(mx, mOld);
      float p0 = __expf(v0 - mx), p1 = __expf(v1 - mx), p2 = __expf(v2 - mx), p3 = __expf(v3 - mx);
      S[g][l] = p0; S[g][l + 16] = p1; S[g][l + 32] = p2; S[g][l + 48] = p3;
      float sum = p0 + p1 + p2 + p3;
      for (int o2 = 8; o2; o2 >>= 1) sum += __shfl_xor(sum, o2, 16);
      if (l == 0) {
        float alpha = __expf(mOld - mx);
        aS[g] = alpha;
        lS[g] = lS[g] * alpha + sum;
        mS[g] = mx;
      }
    }
    __syncthreads();
    if (tid < 192) {
      float a = aS[pr];
      o.x *= a; o.y *= a; o.z *= a; o.w *= a;
#pragma unroll
      for (int c4 = 0; c4 < 16; ++c4) {
        float4 s4 = *(const float4*)&S[pr][c4 * 4];
        float4 v;
        v = *(const float4*)&Vs[c4 * 4 + 0][pch * 4];
        o.x += s4.x * v.x; o.y += s4.x * v.y; o.z += s4.x * v.z; o.w += s4.x * v.w;
        v = *(const float4*)&Vs[c4 * 4 + 1][pch * 4];
        o.x += s4.y * v.x; o.y += s4.y * v.y; o.z += s4.y * v.z; o.w += s4.y * v.w;
        v = *(const float4*)&Vs[c4 * 4 + 2][pch * 4];
        o.x += s4.z * v.x; o.y += s4.z * v.y; o.z += s4.z * v.z; o.w += s4.z * v.w;
        v = *(const float4*)&Vs[c4 * 4 + 3][pch * 4];
        o.x += s4.w * v.x; o.y += s4.w * v.y; o.z += s4.w * v.z; o.w += s4.w * v.w;
      }
    }
    __syncthreads();
  }
  if (tid < 192) {
    float inv = 1.0f / lS[pr];
    o.x *= inv; o.y *= inv; o.z *= inv; o.w *= inv;
    *(float4*)(y + (long)b * 1024 * 192 + (long)(q0 + pr) * 192 + h * 48 + pch * 4) = o;
  }
}

// ---------------- EMA: x[pair1] = 0.8*x[pair1] + 0.2*x[pair0] ----------------
__global__ void k_ema(float* __restrict__ x) {
  int i = blockIdx.x * blockDim.x + threadIdx.x;
  if (i < 196608) x[196608 + i] = 0.8f * x[196608 + i] + 0.2f * x[i];
}

// ---------------- fv (2048x2) -> flow [b][2][1024] ----------------
__global__ void k_fv2flow(const float* __restrict__ fv, float* __restrict__ cur) {
  int i = blockIdx.x * blockDim.x + threadIdx.x;
  if (i < 4096) {
    int b = i >> 11, r = i & 2047;
    int c = r >> 10, p = r & 1023;
    cur[i] = fv[(long)(b * 1024 + p) * 2 + c];
  }
}

// ---------------- warp (bilinear, border clamp); img for pair b is imgbase[(b+1)] --------
__global__ void k_warp(const float* __restrict__ imgbase, const float* __restrict__ flow,
                       float* __restrict__ out, int C, int H, int W) {
  int HW = H * W;
  int per = C * HW;
  int i = blockIdx.x * blockDim.x + threadIdx.x;
  if (i >= 2 * per) return;
  int b = i / per;
  int rem = i - b * per;
  int c = rem / HW;
  int p = rem - c * HW;
  int h = p / W, w = p - h * W;
  const float* img = imgbase + (long)(b + 1) * per;
  const float* fl = flow + (long)b * 2 * HW;
  float x = fminf(fmaxf((float)w + fl[p], 0.0f), (float)(W - 1));
  float yy = fminf(fmaxf((float)h + fl[HW + p], 0.0f), (float)(H - 1));
  int x0 = (int)floorf(x), y0 = (int)floorf(yy);
  int x1 = min(x0 + 1, W - 1), y1 = min(y0 + 1, H - 1);
  float wx = x - (float)x0, wy = yy - (float)y0;
  const float* ic = img + (long)c * HW;
  float v00 = ic[y0 * W + x0], v01 = ic[y0 * W + x1];
  float v10 = ic[y1 * W + x0], v11 = ic[y1 * W + x1];
  out[i] = v00 * (1 - wx) * (1 - wy) + v01 * wx * (1 - wy) + v10 * (1 - wx) * wy + v11 * wx * wy;
}

// ---------------- 3x3 conv phase 1: partial sums over an input-channel split -----------
template <int OCG>
__global__ __launch_bounds__(256) void k_conv_part(
    const float* __restrict__ s0, int c0, long s0bs,
    const float* __restrict__ s1, int c1, long s1bs,
    const float* __restrict__ s2, int c2, long s2bs,
    const float* __restrict__ wT, int OC,
    float* __restrict__ pa, long Sa, int na, float* __restrict__ pb,
    int H, int W, int NS) {
  __shared__ float T[8][18][20];
  int tid = threadIdx.x;
  int nTx = W >> 4;
  int ty0 = (blockIdx.x / nTx) << 4, tx0 = (blockIdx.x % nTx) << 4;
  int oc0 = blockIdx.y * OCG;
  int z = blockIdx.z;
  int b = z / NS, s = z - b * NS;
  int ICT = c0 + c1 + c2;
  int csz = (ICT + NS - 1) / NS;
  int g0 = s * csz, g1 = min(ICT, g0 + csz);
  float acc[OCG] = {};
  int ly = tid >> 4, lx = tid & 15;
  const float* sp0 = s0 + (long)b * s0bs;
  const float* sp1 = s1 ? s1 + (long)b * s1bs : nullptr;
  const float* sp2 = s2 ? s2 + (long)b * s2bs : nullptr;
  for (int gc = g0; gc < g1; gc += 8) {
    int nb = min(8, g1 - gc);
    for (int i = tid; i < nb * 324; i += 256) {
      int bch = i / 324, w2 = i - bch * 324;
      int rr = w2 / 18, cc = w2 - rr * 18;
      int yy = ty0 - 1 + rr, xx = tx0 - 1 + cc;
      int gch = gc + bch;
      const float* sp; int lc;
      if (gch < c0) { sp = sp0; lc = gch; }
      else if (gch < c0 + c1) { sp = sp1; lc = gch - c0; }
      else { sp = sp2; lc = gch - c0 - c1; }
      T[bch][rr][cc] = (yy >= 0 && yy < H && xx >= 0 && xx < W)
                           ? sp[(long)lc * H * W + yy * W + xx] : 0.0f;
    }
    __syncthreads();
    for (int j = 0; j < nb; ++j) {
      float t00 = T[j][ly][lx],     t01 = T[j][ly][lx + 1],     t02 = T[j][ly][lx + 2];
      float t10 = T[j][ly + 1][lx], t11 = T[j][ly + 1][lx + 1], t12 = T[j][ly + 1][lx + 2];
      float t20 = T[j][ly + 2][lx], t21 = T[j][ly + 2][lx + 1], t22 = T[j][ly + 2][lx + 2];
      const float* wp = wT + ((long)(gc + j) * OC + oc0) * 9;
#pragma unroll
      for (int o = 0; o < OCG; ++o) {
        const float* w9 = wp + o * 9;
        acc[o] += t00 * w9[0] + t01 * w9[1] + t02 * w9[2]
                + t10 * w9[3] + t11 * w9[4] + t12 * w9[5]
                + t20 * w9[6] + t21 * w9[7] + t22 * w9[8];
      }
    }
    __syncthreads();
  }
  float* base = (s < na) ? pa + (long)s * Sa : pb + (long)(s - na) * Sa;
  long p = (long)(ty0 + ly) * W + (tx0 + lx);
#pragma unroll
  for (int o = 0; o < OCG; ++o)
    base[((long)b * OC + (oc0 + o)) * (long)(H * W) + p] = acc[o];
}

// phase 2: out = [gelu](bias + sum of partial chunks) [+ res]
__global__ void k_conv_fin(const float* __restrict__ pa, long Sa, int na,
                           const float* __restrict__ pb, int nb2,
                           const float* __restrict__ bias, const float* __restrict__ res,
                           float* __restrict__ out, int OC, int HW, int act, int n) {
  int i = blockIdx.x * blockDim.x + threadIdx.x;
  if (i >= n) return;
  int oc = (i / HW) % OC;
  float v = bias[oc];
  for (int s = 0; s < na; ++s) v += pa[(long)s * Sa + i];
  for (int s = 0; s < nb2; ++s) v += pb[(long)s * Sa + i];
  if (act) v = gelu_exact(v);
  if (res) v += res[i];
  out[i] = v;
}

// ---------------- 2x align-corners bilinear upsample ----------------
__global__ void k_upsample(const float* __restrict__ in, float* __restrict__ out) {
  int i = blockIdx.x * blockDim.x + threadIdx.x;
  if (i >= 2 * 2 * 64 * 64) return;
  int p = i & 4095;
  int bc = i >> 12;
  int oy = p >> 6, ox = p & 63;
  float sx = ox * (31.0f / 63.0f), sy = oy * (31.0f / 63.0f);
  int x0 = (int)sx, y0 = (int)sy;
  int x1 = min(x0 + 1, 31), y1 = min(y0 + 1, 31);
  float wx = sx - x0, wy = sy - y0;
  const float* ic = in + (long)bc * 1024;
  out[i] = ic[y0 * 32 + x0] * (1 - wx) * (1 - wy) + ic[y0 * 32 + x1] * wx * (1 - wy)
         + ic[y1 * 32 + x0] * (1 - wx) * wy      + ic[y1 * 32 + x1] * wx * wy;
}

// ---------------- final write (fp32 -> bf16|fp32 per detected dtype) ----------------
__global__ void k_out(const float* __restrict__ cur2, void* __restrict__ out,
                      const int* __restrict__ fl) {
  int isb = *fl;
  int i = blockIdx.x * blockDim.x + threadIdx.x;
  if (i < 16384) {
    if (isb) ((bf16*)out)[i] = f2bf(cur2[i]);
    else ((float*)out)[i] = cur2[i];
  }
}

extern "C" void kernel_launch(void* const* d_in, const int* in_sizes, int n_in,
                              void* d_out, int out_size, void* d_ws, size_t ws_size,
                              hipStream_t stream) {
  const void* feats_l1 = d_in[0];
  const void* feats_l2 = d_in[1];
  const void* tok_w = d_in[3];
  const void* tok_b = d_in[4];
  const void* lcm_ln1_w = d_in[5];
  const void* lcm_ln1_b = d_in[6];
  const void* lcm_in_w  = d_in[7];
  const void* lcm_in_b  = d_in[8];
  const void* lcm_out_w = d_in[9];
  const void* lcm_out_b = d_in[10];
  const void* lcm_ln2_w = d_in[11];
  const void* lcm_ln2_b = d_in[12];
  const void* lcm_mlp_w1 = d_in[13];
  const void* lcm_mlp_b1 = d_in[14];
  const void* lcm_mlp_w2 = d_in[15];
  const void* lcm_mlp_b2 = d_in[16];
  const void* gtr_ln1_w = d_in[17];
  const void* gtr_ln1_b = d_in[18];
  const void* gtr_in_w  = d_in[19];
  const void* gtr_in_b  = d_in[20];
  const void* gtr_out_w = d_in[21];
  const void* gtr_out_b = d_in[22];
  const void* gtr_ln2_w = d_in[23];
  const void* gtr_ln2_b = d_in[24];
  const void* gtr_mlp_w1 = d_in[25];
  const void* gtr_mlp_b1 = d_in[26];
  const void* gtr_mlp_w2 = d_in[27];
  const void* gtr_mlp_b2 = d_in[28];
  const void* head_w1 = d_in[29];
  const void* head_b1 = d_in[30];
  const void* head_w2 = d_in[31];
  const void* head_b2 = d_in[32];
  const void* ref1_w1 = d_in[33];
  const void* ref1_b1 = d_in[34];
  const void* ref1_w2 = d_in[35];
  const void* ref1_b2 = d_in[36];
  const void* ref0_w1 = d_in[37];
  const void* ref0_b1 = d_in[38];
  const void* ref0_w2 = d_in[39];
  const void* ref0_b2 = d_in[40];
  (void)ws_size; (void)n_in; (void)in_sizes; (void)out_size;

  // ---- workspace layout (fp32; ~17.3 MB, same budget as round 4) ----
  int* flag = (int*)d_ws;
  int* oneflag = (int*)d_ws + 2;
  float* wsf = (float*)d_ws;
  float* F2  = wsf + 16;              // 393216
  float* F1  = F2 + 393216;           // 786432
  float* x   = F1 + 786432;           // 393216
  float* ta  = x + 393216;            // 393216
  float* yb  = ta + 393216;           // 393216
  float* big = yb + 393216;           // 1572864: corrT | qkvb | hid | decoder scratch
  float* fv  = big + 1572864;         // 4096
  float* cur = fv + 4096;             // 4096   [2][2][1024]
  float* cur2 = cur + 4096;           // 16384  [2][2][4096]
  float* cwT1a = cur2 + 16384;        // 297216 : ref1_w1 fp32 transposed [258][128][9]
  float* cb1a  = cwT1a + 297216;      // 128
  float* cwT1b = cb1a + 128;          // 2304   : ref1_w2 [128][2][9]
  float* cb1b  = cwT1b + 2304;        // 16 (2 used)
  float* cwT0a = cb1b + 16;           // 74880  : ref0_w1 [130][64][9]
  float* cb0a  = cwT0a + 74880;       // 64
  float* cwT0b = cb0a + 64;           // 1152   : ref0_w2 [64][2][9]
  float* cb0b  = cwT0b + 1152;        // 16 (2 used)
  bf16* wtok   = (bf16*)(cb0b + 16);  // 12288 bf16 = 6144 floats: padded tokenizer W [192][64]
  float* corrT = big;                 // 2048 x 64 (zero-padded K)
  float* qkvb = big;                  // 2048 x 576
  float* hid  = big;                  // 2048 x 768
  float* wp1  = big;                  // [2][128][1024]
  float* mid1 = big + 262144;         // [2][128][1024]
  float* wp0  = big;                  // [2][64][4096]
  float* mid0 = big + 524288;         // [2][64][4096]
  float* bigtail = big + 1048576;     // 3rd l0-conv1 partial chunk
  float* p1b  = big + 524288;         // l1-conv2 partials

  k_detect<<<1, 256, 0, stream>>>((const unsigned short*)feats_l1, flag);
  k_setone<<<1, 1, 0, stream>>>(oneflag);
  k_cvt<<<1536, 256, 0, stream>>>(feats_l2, F2, 393216, flag);
  k_cvt<<<3072, 256, 0, stream>>>(feats_l1, F1, 786432, flag);
  k_cvt_trans<<<1161, 256, 0, stream>>>(ref1_w1, cwT1a, 128, 258, 297216, flag);
  k_cvt<<<1, 256, 0, stream>>>(ref1_b1, cb1a, 128, flag);
  k_cvt_trans<<<9, 256, 0, stream>>>(ref1_w2, cwT1b, 2, 128, 2304, flag);
  k_cvt<<<1, 256, 0, stream>>>(ref1_b2, cb1b, 2, flag);
  k_cvt_trans<<<293, 256, 0, stream>>>(ref0_w1, cwT0a, 64, 130, 74880, flag);
  k_cvt<<<1, 256, 0, stream>>>(ref0_b1, cb0a, 64, flag);
  k_cvt_trans<<<5, 256, 0, stream>>>(ref0_w2, cwT0b, 2, 64, 1152, flag);
  k_cvt<<<1, 256, 0, stream>>>(ref0_b2, cb0b, 2, flag);
  k_padtokw<<<48, 256, 0, stream>>>(tok_w, wtok, flag);

  // ---- tokens (level 1 only): corr (K padded to 64) then tokenizer GEMM (MFMA) ----
  k_corr<<<dim3(1024, 2), 64, 0, stream>>>(F2, corrT);
  k_gemm_mfma<0, false><<<dim3(3, 32), 256, 0, stream>>>(
      corrT, wtok, 0, tok_b, 192, flag, nullptr, x, 2048, 192, 64, oneflag);

  auto run_block = [&](const void* ln1w, long o1, const void* ln1b, long o2,
                       const void* inw, long o3, const void* inb, long o4,
                       const void* ow, long o5, const void* ob, long o6,
                       const void* ln2w, long o7, const void* ln2b, long o8,
                       const void* w1, long o9, const void* b1, long o10,
                       const void* w2, long o11, const void* b2, long o12) {
    k_ln<<<2048, 64, 0, stream>>>(x, ta, ln1w, o1, ln1b, o2, flag);
    k_gemm_mfma<0, false><<<dim3(9, 32), 256, 0, stream>>>(
        ta, inw, o3, inb, o4, flag, nullptr, qkvb, 2048, 576, 192, flag);
    k_attn<<<dim3(64, 4, 2), 256, 0, stream>>>(qkvb, yb);
    k_gemm_mfma<0, true><<<dim3(3, 32), 256, 0, stream>>>(
        yb, ow, o5, ob, o6, flag, x, x, 2048, 192, 192, flag);
    k_ln<<<2048, 64, 0, stream>>>(x, ta, ln2w, o7, ln2b, o8, flag);
    k_gemm_mfma<1, false><<<dim3(12, 32), 256, 0, stream>>>(
        ta, w1, o9, b1, o10, flag, nullptr, hid, 2048, 768, 192, flag);
    k_gemm_mfma<0, true><<<dim3(3, 32), 256, 0, stream>>>(
        hid, w2, o11, b2, o12, flag, x, x, 2048, 192, 768, flag);
  };

  // ---- LCM: 6 blocks, both pairs batched ----
  for (int i = 0; i < 6; ++i) {
    run_block(lcm_ln1_w, (long)i * 192, lcm_ln1_b, (long)i * 192,
              lcm_in_w, (long)i * 110592, lcm_in_b, (long)i * 576,
              lcm_out_w, (long)i * 36864, lcm_out_b, (long)i * 192,
              lcm_ln2_w, (long)i * 192, lcm_ln2_b, (long)i * 192,
              lcm_mlp_w1, (long)i * 147456, lcm_mlp_b1, (long)i * 768,
              lcm_mlp_w2, (long)i * 147456, lcm_mlp_b2, (long)i * 192);
  }
  k_ema<<<768, 256, 0, stream>>>(x);

  // ---- GTR: 2 blocks ----
  for (int i = 0; i < 2; ++i) {
    run_block(gtr_ln1_w, (long)i * 192, gtr_ln1_b, (long)i * 192,
              gtr_in_w, (long)i * 110592, gtr_in_b, (long)i * 576,
              gtr_out_w, (long)i * 36864, gtr_out_b, (long)i * 192,
              gtr_ln2_w, (long)i * 192, gtr_ln2_b, (long)i * 192,
              gtr_mlp_w1, (long)i * 147456, gtr_mlp_b1, (long)i * 768,
              gtr_mlp_w2, (long)i * 147456, gtr_mlp_b2, (long)i * 192);
  }

  // ---- head -> coarse flow ----
  k_gemm_mfma<1, false><<<dim3(3, 32), 256, 0, stream>>>(
      x, head_w1, 0, head_b1, 0, flag, nullptr, ta, 2048, 192, 192, flag);
  k_gemm<0, false><<<dim3(1, 16), 256, 0, stream>>>(ta, head_w2, 0, head_b2, 0, nullptr, fv,
                                                    2048, 2, 192, 192, flag);
  k_fv2flow<<<16, 256, 0, stream>>>(fv, cur);

  // ---- decoder level 1 (32x32, feats_l2); IC=258 split NS=4 ----
  for (int it = 0; it < 4; ++it) {
    k_warp<<<1024, 256, 0, stream>>>(F2, cur, wp1, 128, 32, 32);
    k_conv_part<8><<<dim3(4, 16, 8), 256, 0, stream>>>(
        F2, 128, 131072, cur, 2, 2048, wp1, 128, 131072,
        cwT1a, 128, x, 262144, 4, nullptr, 32, 32, 4);
    k_conv_fin<<<1024, 256, 0, stream>>>(x, 262144, 4, nullptr, 0, cb1a, nullptr,
                                         mid1, 128, 1024, 1, 262144);
    k_conv_part<2><<<dim3(4, 1, 32), 256, 0, stream>>>(
        mid1, 128, 131072, nullptr, 0, 0, nullptr, 0, 0,
        cwT1b, 2, p1b, 4096, 16, nullptr, 32, 32, 16);
    k_conv_fin<<<32, 256, 0, stream>>>(p1b, 4096, 16, nullptr, 0, cb1b, cur,
                                       cur, 2, 1024, 0, 8192);
  }
  k_upsample<<<64, 256, 0, stream>>>(cur, cur2);

  // ---- decoder level 0 (64x64, feats_l1); IC=130 split NS=3 ----
  for (int it = 0; it < 4; ++it) {
    k_warp<<<2048, 256, 0, stream>>>(F1, cur2, wp0, 64, 64, 64);
    k_conv_part<8><<<dim3(16, 8, 6), 256, 0, stream>>>(
        F1, 64, 262144, cur2, 2, 8192, wp0, 64, 262144,
        cwT0a, 64, x, 524288, 2, bigtail, 64, 64, 3);
    k_conv_fin<<<2048, 256, 0, stream>>>(x, 524288, 2, bigtail, 1, cb0a, nullptr,
                                         mid0, 64, 4096, 1, 524288);
    k_conv_part<2><<<dim3(16, 1, 16), 256, 0, stream>>>(
        mid0, 64, 262144, nullptr, 0, 0, nullptr, 0, 0,
        cwT0b, 2, x, 16384, 8, nullptr, 64, 64, 8);
    k_conv_fin<<<128, 256, 0, stream>>>(x, 16384, 8, nullptr, 0, cb0b, cur2,
                                        cur2, 2, 4096, 0, 32768);
  }

  k_out<<<64, 256, 0, stream>>>(cur2, d_out, flag);
}